// Round 1
// baseline (1612.117 us; speedup 1.0000x reference)
//
#include <hip/hip_runtime.h>
#include <math.h>

#define DEV_INLINE __device__ __forceinline__

// ---------------------------------------------------------------------------
// Config for one (point-cloud, radius-scale) SA computation. 10 total.
// ---------------------------------------------------------------------------
struct Cfg {
  const float* xyz;    // [N,3]
  const float* feat;   // [N,Cfeat] or null
  const float* W0;     // [Cin=3+Cfeat, C0] (already offset for scale)
  const float* W1;     // [C0, C0]
  const float* gb0;    // gamma at [0..C0), beta at [C0..2C0)
  const float* gb1;
  int N, S, Cfeat, C0;
  int logS, logC0;
  int colOff;          // column offset in fused [2048,512]
  int idxOff;          // offset into ushort idx buffer
  int emptyOff;        // offset into int empty buffer
  int statOff;         // offset into double stats buffer (sum0[64],sq0[64],sum1[64],sq1[64])
  float r2;
};
struct AllCfg { Cfg c[10]; };

static const int M = 2048;

// ---------------------------------------------------------------------------
// Ball query: one wave per keypoint, first-S-in-index-order via ballot prefix.
// ---------------------------------------------------------------------------
__global__ __launch_bounds__(256) void k_ballq(AllCfg cfgs, const float* __restrict__ kp,
                                               unsigned short* __restrict__ idxbuf,
                                               int* __restrict__ emptybuf) {
  const Cfg cfg = cfgs.c[blockIdx.y];
  const int lane = threadIdx.x & 63;
  const int wid = (blockIdx.x * blockDim.x + threadIdx.x) >> 6;
  if (wid >= M) return;
  const float qx = kp[wid * 3 + 0], qy = kp[wid * 3 + 1], qz = kp[wid * 3 + 2];
  const int N = cfg.N, S = cfg.S;
  const float r2 = cfg.r2;
  const float* __restrict__ xyz = cfg.xyz;
  unsigned short* out = idxbuf + cfg.idxOff + wid * S;
  int cnt = 0, first = -1;
  for (int base = 0; base < N; base += 64) {
    const int j = base + lane;
    bool inb = false;
    if (j < N) {
      #pragma clang fp contract(off)
      const float dx = qx - xyz[j * 3 + 0];
      const float dy = qy - xyz[j * 3 + 1];
      const float dz = qz - xyz[j * 3 + 2];
      const float d2 = (dx * dx + dy * dy) + dz * dz;
      inb = d2 < r2;
    }
    const unsigned long long msk = __ballot(inb);
    if (msk) {
      if (inb) {
        const int pos = cnt + __popcll(msk & ((1ull << lane) - 1ull));
        if (pos < S) out[pos] = (unsigned short)j;
      }
      if (first < 0) first = base + __builtin_ctzll(msk);
      cnt += __popcll(msk);
      if (cnt >= S) break;
    }
  }
  const unsigned short fillv = (unsigned short)(first < 0 ? 0 : first);
  for (int p = cnt + lane; p < S; p += 64) out[p] = fillv;
  if (lane == 0) emptybuf[cfg.emptyOff + wid] = (first < 0) ? 1 : 0;
}

// ---------------------------------------------------------------------------
// h0[row][co] = (grouped xyz offsets ++ feats) . W0[:,co]   (0 if empty ball)
// ---------------------------------------------------------------------------
DEV_INLINE float h0_elem(const Cfg& cfg, const float* __restrict__ kp,
                         const unsigned short* __restrict__ idxbuf,
                         int row, int co, bool emp) {
  if (emp) return 0.f;
  const int m = row >> cfg.logS;
  const int idx = (int)idxbuf[cfg.idxOff + row];
  const float* p = cfg.xyz + 3 * idx;
  const float gx = p[0] - kp[m * 3 + 0];
  const float gy = p[1] - kp[m * 3 + 1];
  const float gz = p[2] - kp[m * 3 + 2];
  const int C0 = cfg.C0;
  const float* w = cfg.W0 + co;
  float h = gx * w[0] + gy * w[C0] + gz * w[2 * C0];
  const float* f = cfg.feat + (size_t)idx * cfg.Cfeat;
  for (int ci = 0; ci < cfg.Cfeat; ++ci) h += f[ci] * w[(size_t)(3 + ci) * C0];
  return h;
}

// Per-channel sum/sumsq reduction: wave shfl -> LDS -> global double atomics.
DEV_INLINE void stat_reduce(float lsum, float lsq, int C0, int cc,
                            double* gsum, double* gsq) {
  for (int off = 32; off >= C0; off >>= 1) {
    lsum += __shfl_xor(lsum, off);
    lsq  += __shfl_xor(lsq, off);
  }
  __shared__ float sA[64], sB[64];
  if (threadIdx.x < 64) { sA[threadIdx.x] = 0.f; sB[threadIdx.x] = 0.f; }
  __syncthreads();
  if ((int)(threadIdx.x & 63) < C0) { atomicAdd(&sA[cc], lsum); atomicAdd(&sB[cc], lsq); }
  __syncthreads();
  if ((int)threadIdx.x < C0) {
    atomicAdd(&gsum[threadIdx.x], (double)sA[threadIdx.x]);
    atomicAdd(&gsq[threadIdx.x],  (double)sB[threadIdx.x]);
  }
}

// ---------------------------------------------------------------------------
// Pass 1: stats of h0 over all rows.
// ---------------------------------------------------------------------------
__global__ __launch_bounds__(256) void k_stats0(AllCfg cfgs, const float* __restrict__ kp,
                                                const unsigned short* __restrict__ idxbuf,
                                                const int* __restrict__ emptybuf,
                                                double* __restrict__ stats) {
  const Cfg cfg = cfgs.c[blockIdx.y];
  const int C0 = cfg.C0;
  const int total = (M << cfg.logS) << cfg.logC0;
  const int stride = gridDim.x * 256;
  const int t0 = blockIdx.x * 256 + threadIdx.x;
  const int cc = t0 & (C0 - 1);
  float lsum = 0.f, lsq = 0.f;
  for (int e = t0; e < total; e += stride) {
    const int row = e >> cfg.logC0;
    const int m = row >> cfg.logS;
    const bool emp = emptybuf[cfg.emptyOff + m] != 0;
    const float h = h0_elem(cfg, kp, idxbuf, row, cc, emp);
    lsum += h; lsq += h * h;
  }
  stat_reduce(lsum, lsq, C0, cc, stats + cfg.statOff, stats + cfg.statOff + 64);
}

// ---------------------------------------------------------------------------
// Pass 2: recompute h0, BN0+ReLU -> a0 (LDS), h1 = a0 @ W1, stats of h1.
// ---------------------------------------------------------------------------
__global__ __launch_bounds__(256) void k_stats1(AllCfg cfgs, const float* __restrict__ kp,
                                                const unsigned short* __restrict__ idxbuf,
                                                const int* __restrict__ emptybuf,
                                                double* __restrict__ stats) {
  const Cfg cfg = cfgs.c[blockIdx.y];
  const int C0 = cfg.C0;
  const int tid = threadIdx.x;
  const int rl = tid >> cfg.logC0;
  const int cc = tid & (C0 - 1);
  const int rpp = 256 >> cfg.logC0;
  const int nrows = M << cfg.logS;
  const double n = (double)nrows;
  const double* st = stats + cfg.statOff;
  const double mu = st[cc] / n;
  const double var = st[64 + cc] / n - mu * mu;
  const double inv = 1.0 / sqrt(var + 1e-5);
  const double g0 = (double)cfg.gb0[cc], b0 = (double)cfg.gb0[C0 + cc];
  const float sc = (float)(inv * g0);
  const float sh = (float)(b0 - mu * inv * g0);
  __shared__ float a0[256];
  float lsum = 0.f, lsq = 0.f;
  const int chunks = nrows >> (8 - cfg.logC0);  // nrows / rpp
  const float* w1 = cfg.W1 + cc;
  for (int ch = blockIdx.x; ch < chunks; ch += gridDim.x) {
    const int row = ch * rpp + rl;
    const int m = row >> cfg.logS;
    const bool emp = emptybuf[cfg.emptyOff + m] != 0;
    const float h = h0_elem(cfg, kp, idxbuf, row, cc, emp);
    a0[tid] = fmaxf(h * sc + sh, 0.f);
    __syncthreads();
    float h1 = 0.f;
    const float* ar = a0 + (tid - cc);  // rl*C0
    for (int ci = 0; ci < C0; ++ci) h1 += ar[ci] * w1[(size_t)ci * C0];
    lsum += h1; lsq += h1 * h1;
    __syncthreads();
  }
  stat_reduce(lsum, lsq, C0, cc, stats + cfg.statOff + 128, stats + cfg.statOff + 192);
}

// ---------------------------------------------------------------------------
// Pass 3: one block per keypoint: a0 -> LDS, h1, BN1+ReLU, max over S -> fused.
// ---------------------------------------------------------------------------
__global__ __launch_bounds__(256) void k_final(AllCfg cfgs, const float* __restrict__ kp,
                                               const unsigned short* __restrict__ idxbuf,
                                               const int* __restrict__ emptybuf,
                                               const double* __restrict__ stats,
                                               float* __restrict__ fused) {
  const Cfg cfg = cfgs.c[blockIdx.y];
  const int C0 = cfg.C0, S = cfg.S;
  const int m = blockIdx.x;
  const int tid = threadIdx.x;
  const int cc = tid & (C0 - 1);
  const int nrows = M << cfg.logS;
  const double n = (double)nrows;
  const double* st = stats + cfg.statOff;
  const double mu0 = st[cc] / n;
  const double v0 = st[64 + cc] / n - mu0 * mu0;
  const double i0 = 1.0 / sqrt(v0 + 1e-5);
  const double g0 = (double)cfg.gb0[cc], b0 = (double)cfg.gb0[C0 + cc];
  const float sc0 = (float)(i0 * g0), sh0 = (float)(b0 - mu0 * i0 * g0);
  const double mu1 = st[128 + cc] / n;
  const double v1 = st[192 + cc] / n - mu1 * mu1;
  const double i1 = 1.0 / sqrt(v1 + 1e-5);
  const double g1 = (double)cfg.gb1[cc], b1 = (double)cfg.gb1[C0 + cc];
  const float sc1 = (float)(i1 * g1), sh1 = (float)(b1 - mu1 * i1 * g1);

  __shared__ float a0[2048];   // S*C0 <= 2048
  __shared__ float mx[64];
  if (tid < 64) mx[tid] = 0.f;
  const bool emp = emptybuf[cfg.emptyOff + m] != 0;
  const int elems = S << cfg.logC0;
  for (int e = tid; e < elems; e += 256) {
    const int s = e >> cfg.logC0;
    const int row = (m << cfg.logS) + s;
    const float h = h0_elem(cfg, kp, idxbuf, row, cc, emp);
    a0[e] = fmaxf(h * sc0 + sh0, 0.f);
  }
  __syncthreads();
  const float* w1 = cfg.W1 + cc;
  for (int e = tid; e < elems; e += 256) {
    const float* ar = a0 + (e - cc);  // s*C0
    float h1 = 0.f;
    for (int ci = 0; ci < C0; ++ci) h1 += ar[ci] * w1[(size_t)ci * C0];
    const float a1v = fmaxf(h1 * sc1 + sh1, 0.f);
    atomicMax((int*)&mx[cc], __float_as_int(a1v));  // values >= 0: int order ok
  }
  __syncthreads();
  if (tid < C0) fused[(size_t)m * 512 + cfg.colOff + tid] = mx[tid];
}

// ---------------------------------------------------------------------------
// BEV bilinear interpolation -> fused cols [0,128)
// ---------------------------------------------------------------------------
__global__ __launch_bounds__(256) void k_bev(const float* __restrict__ kp,
                                             const float* __restrict__ bev,
                                             float* __restrict__ fused) {
  const int e = blockIdx.x * 256 + threadIdx.x;  // 2048*128
  const int c = e & 127, m = e >> 7;
  float x, y;
  {
    #pragma clang fp contract(off)
    x = ((kp[m * 3 + 0] - (-25.6f)) / 0.1f) / 8.0f;
    y = ((kp[m * 3 + 1] - (-25.6f)) / 0.1f) / 8.0f;
  }
  const int x0 = (int)floorf(x), y0 = (int)floorf(y);
  const int x1 = x0 + 1, y1 = y0 + 1;
  const int x0c = min(max(x0, 0), 63), x1c = min(max(x1, 0), 63);
  const int y0c = min(max(y0, 0), 63), y1c = min(max(y1, 0), 63);
  float wa, wb, wc, wd;
  {
    #pragma clang fp contract(off)
    wa = ((float)x1c - x) * ((float)y1c - y);
    wb = ((float)x1c - x) * (y - (float)y0c);
    wc = (x - (float)x0c) * ((float)y1c - y);
    wd = (x - (float)x0c) * (y - (float)y0c);
  }
  const float Ia = bev[((y0c << 6) + x0c) * 128 + c];
  const float Ib = bev[((y1c << 6) + x0c) * 128 + c];
  const float Ic = bev[((y0c << 6) + x1c) * 128 + c];
  const float Id = bev[((y1c << 6) + x1c) * 128 + c];
  {
    #pragma clang fp contract(off)
    fused[(size_t)m * 512 + c] = Ia * wa + Ib * wb + Ic * wc + Id * wd;
  }
}

// ---------------------------------------------------------------------------
// Fusion: h = fused[2048,512] @ fus_W[512,32], stats over M
// ---------------------------------------------------------------------------
__global__ __launch_bounds__(256) void k_fus_mm(const float* __restrict__ fused,
                                               const float* __restrict__ fusW,
                                               float* __restrict__ hbuf,
                                               double* __restrict__ stats) {
  const int e = blockIdx.x * 256 + threadIdx.x;  // 65536
  const int k = e & 31;
  const int m = e >> 5;
  const float* fr = fused + (size_t)m * 512;
  const float* w = fusW + k;
  float h = 0.f;
  for (int c = 0; c < 512; ++c) h += fr[c] * w[(size_t)c * 32];
  hbuf[e] = h;
  stat_reduce(h, h * h, 32, k, stats + 2560, stats + 2560 + 32);
}

__global__ __launch_bounds__(256) void k_fus_out(const float* __restrict__ hbuf,
                                                 const double* __restrict__ stats,
                                                 const float* __restrict__ fgb,
                                                 float* __restrict__ out) {
  const int e = blockIdx.x * 256 + threadIdx.x;
  const int k = e & 31;
  const double n = 2048.0;
  const double* st = stats + 2560;
  const double mu = st[k] / n;
  const double v = st[32 + k] / n - mu * mu;
  const double inv = 1.0 / sqrt(v + 1e-5);
  const double g = (double)fgb[k], b = (double)fgb[32 + k];
  out[e] = fmaxf((float)(inv * g) * hbuf[e] + (float)(b - mu * inv * g), 0.f);
}

// ---------------------------------------------------------------------------
extern "C" void kernel_launch(void* const* d_in, const int* in_sizes, int n_in,
                              void* d_out, int out_size, void* d_ws, size_t ws_size,
                              hipStream_t stream) {
  (void)in_sizes; (void)n_in; (void)out_size;

  const float* kp   = (const float*)d_in[0];
  const float* raw  = (const float*)d_in[1];
  const float* bev  = (const float*)d_in[2];
  const float* c1x  = (const float*)d_in[3];
  const float* c1f  = (const float*)d_in[4];
  const float* c2x  = (const float*)d_in[5];
  const float* c2f  = (const float*)d_in[6];
  const float* c3x  = (const float*)d_in[7];
  const float* c3f  = (const float*)d_in[8];
  const float* c4x  = (const float*)d_in[9];
  const float* c4f  = (const float*)d_in[10];
  const float* fusW = (const float*)d_in[31];
  const float* fgb  = (const float*)d_in[32];

  // ws layout
  char* ws = (char*)d_ws;
  double* stats = (double*)ws;                                  // 2624 doubles (20992 B)
  unsigned short* idxbuf = (unsigned short*)(ws + 32768);       // 10*65536 ushort (1310720 B)
  int* emptybuf = (int*)(ws + 32768 + 1310720);                 // 10*2048 int (81920 B)
  float* fused  = (float*)(ws + 1425408);                       // 2048*512 f32 (4194304 B)
  float* hbuf   = (float*)(ws + 1425408 + 4194304);             // 2048*32 f32 (262144 B)
  const size_t need = 1425408 + 4194304 + 262144;
  if (ws_size < need) return;  // fail loudly via wrong output rather than corrupt

  AllCfg cfgs;
  auto setCfg = [&](int i, const float* xyz, const float* feat, int N, int Cf, int C0, int S,
                    double r, const float* W0b, const float* W1b, const float* g0b,
                    const float* g1b, int sIdx, int col) {
    Cfg& c = cfgs.c[i];
    const int Cin = 3 + Cf;
    c.xyz = xyz; c.feat = feat;
    c.W0 = W0b + (size_t)sIdx * Cin * C0;
    c.W1 = W1b + (size_t)sIdx * C0 * C0;
    c.gb0 = g0b + (size_t)sIdx * 2 * C0;
    c.gb1 = g1b + (size_t)sIdx * 2 * C0;
    c.N = N; c.S = S; c.Cfeat = Cf; c.C0 = C0;
    c.logS = (S == 16) ? 4 : 5;
    c.logC0 = (C0 == 16) ? 4 : ((C0 == 32) ? 5 : 6);
    c.colOff = col;
    c.idxOff = i * 65536;
    c.emptyOff = i * 2048;
    c.statOff = i * 256;
    c.r2 = (float)(r * r);  // double square then cast, matching JAX weak-type promotion
  };

  const float* rW0 = (const float*)d_in[11]; const float* rW1 = (const float*)d_in[12];
  const float* rg0 = (const float*)d_in[13]; const float* rg1 = (const float*)d_in[14];
  const float* aW0 = (const float*)d_in[15]; const float* aW1 = (const float*)d_in[16];
  const float* ag0 = (const float*)d_in[17]; const float* ag1 = (const float*)d_in[18];
  const float* bW0 = (const float*)d_in[19]; const float* bW1 = (const float*)d_in[20];
  const float* bg0 = (const float*)d_in[21]; const float* bg1 = (const float*)d_in[22];
  const float* cW0 = (const float*)d_in[23]; const float* cW1 = (const float*)d_in[24];
  const float* cg0 = (const float*)d_in[25]; const float* cg1 = (const float*)d_in[26];
  const float* dW0 = (const float*)d_in[27]; const float* dW1 = (const float*)d_in[28];
  const float* dg0 = (const float*)d_in[29]; const float* dg1 = (const float*)d_in[30];

  setCfg(0, raw, nullptr, 30000,  0, 16, 16, 0.4, rW0, rW1, rg0, rg1, 0, 128);
  setCfg(1, raw, nullptr, 30000,  0, 16, 16, 0.8, rW0, rW1, rg0, rg1, 1, 144);
  setCfg(2, c1x, c1f,     30000, 16, 16, 16, 0.4, aW0, aW1, ag0, ag1, 0, 160);
  setCfg(3, c1x, c1f,     30000, 16, 16, 16, 0.8, aW0, aW1, ag0, ag1, 1, 176);
  setCfg(4, c2x, c2f,     16000, 32, 32, 16, 0.8, bW0, bW1, bg0, bg1, 0, 192);
  setCfg(5, c2x, c2f,     16000, 32, 32, 32, 1.2, bW0, bW1, bg0, bg1, 1, 224);
  setCfg(6, c3x, c3f,      8000, 64, 64, 16, 1.2, cW0, cW1, cg0, cg1, 0, 256);
  setCfg(7, c3x, c3f,      8000, 64, 64, 32, 2.4, cW0, cW1, cg0, cg1, 1, 320);
  setCfg(8, c4x, c4f,      4000, 64, 64, 16, 2.4, dW0, dW1, dg0, dg1, 0, 384);
  setCfg(9, c4x, c4f,      4000, 64, 64, 32, 4.8, dW0, dW1, dg0, dg1, 1, 448);

  hipMemsetAsync(stats, 0, 2624 * sizeof(double), stream);
  k_bev<<<dim3(1024), 256, 0, stream>>>(kp, bev, fused);
  k_ballq<<<dim3(512, 10), 256, 0, stream>>>(cfgs, kp, idxbuf, emptybuf);
  k_stats0<<<dim3(256, 10), 256, 0, stream>>>(cfgs, kp, idxbuf, emptybuf, stats);
  k_stats1<<<dim3(512, 10), 256, 0, stream>>>(cfgs, kp, idxbuf, emptybuf, stats);
  k_final<<<dim3(2048, 10), 256, 0, stream>>>(cfgs, kp, idxbuf, emptybuf, stats, fused);
  k_fus_mm<<<dim3(256), 256, 0, stream>>>(fused, fusW, hbuf, stats);
  k_fus_out<<<dim3(256), 256, 0, stream>>>(hbuf, stats, fgb, (float*)d_out);
}

// Round 2
// 544.311 us; speedup vs baseline: 2.9618x; 2.9618x over previous
//
#include <hip/hip_runtime.h>
#include <math.h>

#define DEV_INLINE __device__ __forceinline__

// ---------------------------------------------------------------------------
// Config for one (point-cloud, radius-scale) SA computation. 10 total.
// ---------------------------------------------------------------------------
struct Cfg {
  const float* xyz;    // [N,3]
  const float* feat;   // [N,Cfeat] or null
  const float* W0;     // [Cin=3+Cfeat, C0] (already offset for scale)
  const float* W1;     // [C0, C0]
  const float* gb0;    // gamma at [0..C0), beta at [C0..2C0)
  const float* gb1;
  int N, S, Cfeat, C0;
  int logS, logC0;
  int colOff;          // column offset in fused [2048,512]
  int idxOff;          // offset into ushort idx buffer
  int emptyOff;        // offset into int empty buffer
  int statOff;         // offset into double stats buffer (sum0[64],sq0[64],sum1[64],sq1[64])
  int mmOff;           // offset into max/min float buffers (cells m*C0+cc)
  float r2;
};
struct AllCfg { Cfg c[10]; };

static const int M = 2048;

DEV_INLINE unsigned fkey(float f) {
  unsigned u = __float_as_uint(f);
  return (u & 0x80000000u) ? ~u : (u | 0x80000000u);
}
DEV_INLINE float funkey(unsigned k) {
  return __uint_as_float((k & 0x80000000u) ? (k & 0x7fffffffu) : ~k);
}

// ---------------------------------------------------------------------------
// Ball query: one wave per keypoint, first-S-in-index-order via ballot prefix.
// ---------------------------------------------------------------------------
__global__ __launch_bounds__(256) void k_ballq(AllCfg cfgs, const float* __restrict__ kp,
                                               unsigned short* __restrict__ idxbuf,
                                               int* __restrict__ emptybuf) {
  const Cfg cfg = cfgs.c[blockIdx.y];
  const int lane = threadIdx.x & 63;
  const int wid = (blockIdx.x * blockDim.x + threadIdx.x) >> 6;
  if (wid >= M) return;
  const float qx = kp[wid * 3 + 0], qy = kp[wid * 3 + 1], qz = kp[wid * 3 + 2];
  const int N = cfg.N, S = cfg.S;
  const float r2 = cfg.r2;
  const float* __restrict__ xyz = cfg.xyz;
  unsigned short* out = idxbuf + cfg.idxOff + wid * S;
  int cnt = 0, first = -1;
  for (int base = 0; base < N; base += 64) {
    const int j = base + lane;
    bool inb = false;
    if (j < N) {
      #pragma clang fp contract(off)
      const float dx = qx - xyz[j * 3 + 0];
      const float dy = qy - xyz[j * 3 + 1];
      const float dz = qz - xyz[j * 3 + 2];
      const float d2 = (dx * dx + dy * dy) + dz * dz;
      inb = d2 < r2;
    }
    const unsigned long long msk = __ballot(inb);
    if (msk) {
      if (inb) {
        const int pos = cnt + __popcll(msk & ((1ull << lane) - 1ull));
        if (pos < S) out[pos] = (unsigned short)j;
      }
      if (first < 0) first = base + __builtin_ctzll(msk);
      cnt += __popcll(msk);
      if (cnt >= S) break;
    }
  }
  const unsigned short fillv = (unsigned short)(first < 0 ? 0 : first);
  for (int p = cnt + lane; p < S; p += 64) out[p] = fillv;
  if (lane == 0) emptybuf[cfg.emptyOff + wid] = (first < 0) ? 1 : 0;
}

// ---------------------------------------------------------------------------
// Shared helpers for templated tile kernels
// ---------------------------------------------------------------------------
template<int CIN, int S>
DEV_INLINE void stage_rows(const Cfg& cfg, const float* __restrict__ kp,
                           const unsigned short* __restrict__ idxbuf,
                           const int* __restrict__ emptybuf,
                           int base, float (*in_lds)[(CIN + 3) & ~3]) {
  const int tid = threadIdx.x;
  const int r = tid >> 2, j = tid & 3;
  const int grow = base + r;
  const int m = grow >> ((S == 16) ? 4 : 5);
  const bool emp = emptybuf[cfg.emptyOff + m] != 0;
  const int idx = (int)idxbuf[cfg.idxOff + grow];
  float* dst = in_lds[r];
  if (j == 0) {
    if (emp) { dst[0] = 0.f; dst[1] = 0.f; dst[2] = 0.f; }
    else {
      const float* p = cfg.xyz + 3 * idx;
      dst[0] = p[0] - kp[m * 3 + 0];
      dst[1] = p[1] - kp[m * 3 + 1];
      dst[2] = p[2] - kp[m * 3 + 2];
    }
  }
  if constexpr (CIN > 3) {
    constexpr int CF4 = (CIN - 3) / 4;
    const float4* f4 = (const float4*)cfg.feat + (size_t)idx * CF4;
    for (int c = j; c < CF4; c += 4) {
      float4 v;
      if (emp) v = make_float4(0.f, 0.f, 0.f, 0.f); else v = f4[c];
      dst[3 + 4 * c] = v.x; dst[4 + 4 * c] = v.y;
      dst[5 + 4 * c] = v.z; dst[6 + 4 * c] = v.w;
    }
  }
}

template<int CIN>
DEV_INLINE float dotw(const float* __restrict__ in, const float* __restrict__ w) {
  float h = 0.f;
  #pragma unroll
  for (int ci = 0; ci < CIN; ++ci) h += in[ci] * w[ci];
  return h;
}

// Per-channel sum/sumsq reduction with explicit LDS scratch (reused tile mem).
DEV_INLINE void stat_reduce_s(float lsum, float lsq, int C0, int cc,
                              float* sA, float* sB, double* gsum, double* gsq) {
  __syncthreads();   // prior readers of aliased scratch must be done
  for (int off = 32; off >= C0; off >>= 1) {
    lsum += __shfl_xor(lsum, off);
    lsq  += __shfl_xor(lsq, off);
  }
  if (threadIdx.x < 64) { sA[threadIdx.x] = 0.f; sB[threadIdx.x] = 0.f; }
  __syncthreads();
  if ((int)(threadIdx.x & 63) < C0) { atomicAdd(&sA[cc], lsum); atomicAdd(&sB[cc], lsq); }
  __syncthreads();
  if ((int)threadIdx.x < C0) {
    atomicAdd(&gsum[threadIdx.x], (double)sA[threadIdx.x]);
    atomicAdd(&gsq[threadIdx.x],  (double)sB[threadIdx.x]);
  }
}

// ---------------------------------------------------------------------------
// P1: h0 stats. One 64-row tile per block.
// ---------------------------------------------------------------------------
template<int C0, int CIN, int S>
__device__ __forceinline__ void p1_impl(const Cfg& cfg, const float* __restrict__ kp,
                                        const unsigned short* __restrict__ idxbuf,
                                        const int* __restrict__ emptybuf,
                                        double* __restrict__ stats, char* smem) {
  if ((int)blockIdx.x >= 32 * S) return;
  constexpr int CP = (CIN + 3) & ~3;
  constexpr int STEP = 256 / C0;
  constexpr int RPT = 64 / STEP;
  constexpr int LOGC0 = (C0 == 16) ? 4 : ((C0 == 32) ? 5 : 6);
  float (*in_lds)[CP] = (float(*)[CP])smem;
  const int tid = threadIdx.x;
  const int base = blockIdx.x * 64;
  stage_rows<CIN, S>(cfg, kp, idxbuf, emptybuf, base, in_lds);
  const int cc = tid & (C0 - 1);
  const int rg = tid >> LOGC0;
  float w0[CIN];
  #pragma unroll
  for (int ci = 0; ci < CIN; ++ci) w0[ci] = cfg.W0[ci * C0 + cc];
  __syncthreads();
  float lsum = 0.f, lsq = 0.f;
  for (int rr = 0; rr < RPT; ++rr) {
    const float h = dotw<CIN>(in_lds[rg + rr * STEP], w0);
    lsum += h; lsq += h * h;
  }
  stat_reduce_s(lsum, lsq, C0, cc, (float*)smem, (float*)smem + 64,
                stats + cfg.statOff, stats + cfg.statOff + 64);
}

__global__ __launch_bounds__(256) void k_p1_all(AllCfg cfgs, const float* __restrict__ kp,
                                                const unsigned short* __restrict__ idxbuf,
                                                const int* __restrict__ emptybuf,
                                                double* __restrict__ stats) {
  __shared__ char smem[18432];
  switch (blockIdx.y) {
    case 0: p1_impl<16, 3, 16>(cfgs.c[0], kp, idxbuf, emptybuf, stats, smem); break;
    case 1: p1_impl<16, 3, 16>(cfgs.c[1], kp, idxbuf, emptybuf, stats, smem); break;
    case 2: p1_impl<16, 19, 16>(cfgs.c[2], kp, idxbuf, emptybuf, stats, smem); break;
    case 3: p1_impl<16, 19, 16>(cfgs.c[3], kp, idxbuf, emptybuf, stats, smem); break;
    case 4: p1_impl<32, 35, 16>(cfgs.c[4], kp, idxbuf, emptybuf, stats, smem); break;
    case 5: p1_impl<32, 35, 32>(cfgs.c[5], kp, idxbuf, emptybuf, stats, smem); break;
    case 6: p1_impl<64, 67, 16>(cfgs.c[6], kp, idxbuf, emptybuf, stats, smem); break;
    case 7: p1_impl<64, 67, 32>(cfgs.c[7], kp, idxbuf, emptybuf, stats, smem); break;
    case 8: p1_impl<64, 67, 16>(cfgs.c[8], kp, idxbuf, emptybuf, stats, smem); break;
    case 9: p1_impl<64, 67, 32>(cfgs.c[9], kp, idxbuf, emptybuf, stats, smem); break;
  }
}

// ---------------------------------------------------------------------------
// P2: recompute h0 -> BN0+ReLU -> a0 (LDS) -> h1, h1 stats + per-(m,cc) max/min.
// ---------------------------------------------------------------------------
template<int C0, int CIN, int S>
__device__ __forceinline__ void p2_impl(const Cfg& cfg, const float* __restrict__ kp,
                                        const unsigned short* __restrict__ idxbuf,
                                        const int* __restrict__ emptybuf,
                                        double* __restrict__ stats,
                                        float* __restrict__ maxbuf,
                                        float* __restrict__ minbuf, char* smem) {
  if ((int)blockIdx.x >= 32 * S) return;
  constexpr int CP = (CIN + 3) & ~3;
  constexpr int STEP = 256 / C0;
  constexpr int RPT = 64 / STEP;
  constexpr int LOGC0 = (C0 == 16) ? 4 : ((C0 == 32) ? 5 : 6);
  constexpr int LOGS = (S == 16) ? 4 : 5;
  constexpr int NM = 64 / S;
  float (*in_lds)[CP] = (float(*)[CP])smem;
  float (*a0_lds)[C0] = (float(*)[C0])(smem + 64 * CP * 4);
  unsigned* mxl = (unsigned*)(smem + 64 * CP * 4 + 64 * C0 * 4);
  unsigned* mnl = mxl + NM * C0;
  const int tid = threadIdx.x;
  const int base = blockIdx.x * 64;
  stage_rows<CIN, S>(cfg, kp, idxbuf, emptybuf, base, in_lds);
  if (tid < NM * C0) { mxl[tid] = 0u; mnl[tid] = 0xFFFFFFFFu; }
  const int cc = tid & (C0 - 1);
  const int rg = tid >> LOGC0;
  float w0[CIN], w1[C0];
  #pragma unroll
  for (int ci = 0; ci < CIN; ++ci) w0[ci] = cfg.W0[ci * C0 + cc];
  #pragma unroll
  for (int ci = 0; ci < C0; ++ci) w1[ci] = cfg.W1[ci * C0 + cc];
  const double n = (double)(2048 * S);
  const double* st = stats + cfg.statOff;
  const double mu = st[cc] / n;
  const double var = st[64 + cc] / n - mu * mu;
  const double inv = 1.0 / sqrt(var + 1e-5);
  const double g0 = (double)cfg.gb0[cc], b0 = (double)cfg.gb0[C0 + cc];
  const float sc0 = (float)(inv * g0), sh0 = (float)(b0 - mu * inv * g0);
  __syncthreads();
  for (int rr = 0; rr < RPT; ++rr) {
    const int r = rg + rr * STEP;
    const float h = dotw<CIN>(in_lds[r], w0);
    a0_lds[r][cc] = fmaxf(h * sc0 + sh0, 0.f);
  }
  __syncthreads();
  float lsum = 0.f, lsq = 0.f;
  for (int rr = 0; rr < RPT; ++rr) {
    const int r = rg + rr * STEP;
    float h1 = 0.f;
    #pragma unroll
    for (int ci = 0; ci < C0; ++ci) h1 += a0_lds[r][ci] * w1[ci];
    lsum += h1; lsq += h1 * h1;
    const unsigned k = fkey(h1);
    atomicMax(&mxl[(r >> LOGS) * C0 + cc], k);
    atomicMin(&mnl[(r >> LOGS) * C0 + cc], k);
  }
  stat_reduce_s(lsum, lsq, C0, cc, (float*)in_lds, (float*)in_lds + 64,
                stats + cfg.statOff + 128, stats + cfg.statOff + 192);
  __syncthreads();
  if (tid < NM * C0) {
    const int gcell = (base >> LOGS) * C0 + tid;
    maxbuf[cfg.mmOff + gcell] = funkey(mxl[tid]);
    minbuf[cfg.mmOff + gcell] = funkey(mnl[tid]);
  }
}

__global__ __launch_bounds__(256) void k_p2_all(AllCfg cfgs, const float* __restrict__ kp,
                                                const unsigned short* __restrict__ idxbuf,
                                                const int* __restrict__ emptybuf,
                                                double* __restrict__ stats,
                                                float* __restrict__ maxbuf,
                                                float* __restrict__ minbuf) {
  __shared__ char smem[36864];
  switch (blockIdx.y) {
    case 0: p2_impl<16, 3, 16>(cfgs.c[0], kp, idxbuf, emptybuf, stats, maxbuf, minbuf, smem); break;
    case 1: p2_impl<16, 3, 16>(cfgs.c[1], kp, idxbuf, emptybuf, stats, maxbuf, minbuf, smem); break;
    case 2: p2_impl<16, 19, 16>(cfgs.c[2], kp, idxbuf, emptybuf, stats, maxbuf, minbuf, smem); break;
    case 3: p2_impl<16, 19, 16>(cfgs.c[3], kp, idxbuf, emptybuf, stats, maxbuf, minbuf, smem); break;
    case 4: p2_impl<32, 35, 16>(cfgs.c[4], kp, idxbuf, emptybuf, stats, maxbuf, minbuf, smem); break;
    case 5: p2_impl<32, 35, 32>(cfgs.c[5], kp, idxbuf, emptybuf, stats, maxbuf, minbuf, smem); break;
    case 6: p2_impl<64, 67, 16>(cfgs.c[6], kp, idxbuf, emptybuf, stats, maxbuf, minbuf, smem); break;
    case 7: p2_impl<64, 67, 32>(cfgs.c[7], kp, idxbuf, emptybuf, stats, maxbuf, minbuf, smem); break;
    case 8: p2_impl<64, 67, 16>(cfgs.c[8], kp, idxbuf, emptybuf, stats, maxbuf, minbuf, smem); break;
    case 9: p2_impl<64, 67, 32>(cfgs.c[9], kp, idxbuf, emptybuf, stats, maxbuf, minbuf, smem); break;
  }
}

// ---------------------------------------------------------------------------
// Finalize: apply folded BN1 + ReLU at the h1 extremum (monotone => exact max).
// ---------------------------------------------------------------------------
__global__ __launch_bounds__(256) void k_fin(AllCfg cfgs, const double* __restrict__ stats,
                                             const float* __restrict__ maxbuf,
                                             const float* __restrict__ minbuf,
                                             float* __restrict__ fused) {
  const Cfg cfg = cfgs.c[blockIdx.y];
  const int C0 = cfg.C0;
  const int e = blockIdx.x * 256 + threadIdx.x;
  if (e >= 2048 * C0) return;
  const int cc = e & (C0 - 1);
  const int m = e >> cfg.logC0;
  const double n = (double)(2048 * cfg.S);
  const double* st = stats + cfg.statOff;
  const double mu = st[128 + cc] / n;
  const double v = st[192 + cc] / n - mu * mu;
  const double inv = 1.0 / sqrt(v + 1e-5);
  const double g = (double)cfg.gb1[cc], b = (double)cfg.gb1[C0 + cc];
  const float sc = (float)(inv * g), sh = (float)(b - mu * inv * g);
  const float x = (sc >= 0.f) ? maxbuf[cfg.mmOff + e] : minbuf[cfg.mmOff + e];
  fused[(size_t)m * 512 + cfg.colOff + cc] = fmaxf(sc * x + sh, 0.f);
}

// ---------------------------------------------------------------------------
// Old path (fallback when ws too small): stats0/stats1/final recompute chain.
// ---------------------------------------------------------------------------
DEV_INLINE float h0_elem(const Cfg& cfg, const float* __restrict__ kp,
                         const unsigned short* __restrict__ idxbuf,
                         int row, int co, bool emp) {
  if (emp) return 0.f;
  const int m = row >> cfg.logS;
  const int idx = (int)idxbuf[cfg.idxOff + row];
  const float* p = cfg.xyz + 3 * idx;
  const float gx = p[0] - kp[m * 3 + 0];
  const float gy = p[1] - kp[m * 3 + 1];
  const float gz = p[2] - kp[m * 3 + 2];
  const int C0 = cfg.C0;
  const float* w = cfg.W0 + co;
  float h = gx * w[0] + gy * w[C0] + gz * w[2 * C0];
  const float* f = cfg.feat + (size_t)idx * cfg.Cfeat;
  for (int ci = 0; ci < cfg.Cfeat; ++ci) h += f[ci] * w[(size_t)(3 + ci) * C0];
  return h;
}

DEV_INLINE void stat_reduce(float lsum, float lsq, int C0, int cc,
                            double* gsum, double* gsq) {
  for (int off = 32; off >= C0; off >>= 1) {
    lsum += __shfl_xor(lsum, off);
    lsq  += __shfl_xor(lsq, off);
  }
  __shared__ float sA[64], sB[64];
  if (threadIdx.x < 64) { sA[threadIdx.x] = 0.f; sB[threadIdx.x] = 0.f; }
  __syncthreads();
  if ((int)(threadIdx.x & 63) < C0) { atomicAdd(&sA[cc], lsum); atomicAdd(&sB[cc], lsq); }
  __syncthreads();
  if ((int)threadIdx.x < C0) {
    atomicAdd(&gsum[threadIdx.x], (double)sA[threadIdx.x]);
    atomicAdd(&gsq[threadIdx.x],  (double)sB[threadIdx.x]);
  }
}

__global__ __launch_bounds__(256) void k_stats0(AllCfg cfgs, const float* __restrict__ kp,
                                                const unsigned short* __restrict__ idxbuf,
                                                const int* __restrict__ emptybuf,
                                                double* __restrict__ stats) {
  const Cfg cfg = cfgs.c[blockIdx.y];
  const int C0 = cfg.C0;
  const int total = (M << cfg.logS) << cfg.logC0;
  const int stride = gridDim.x * 256;
  const int t0 = blockIdx.x * 256 + threadIdx.x;
  const int cc = t0 & (C0 - 1);
  float lsum = 0.f, lsq = 0.f;
  for (int e = t0; e < total; e += stride) {
    const int row = e >> cfg.logC0;
    const int m = row >> cfg.logS;
    const bool emp = emptybuf[cfg.emptyOff + m] != 0;
    const float h = h0_elem(cfg, kp, idxbuf, row, cc, emp);
    lsum += h; lsq += h * h;
  }
  stat_reduce(lsum, lsq, C0, cc, stats + cfg.statOff, stats + cfg.statOff + 64);
}

__global__ __launch_bounds__(256) void k_stats1(AllCfg cfgs, const float* __restrict__ kp,
                                                const unsigned short* __restrict__ idxbuf,
                                                const int* __restrict__ emptybuf,
                                                double* __restrict__ stats) {
  const Cfg cfg = cfgs.c[blockIdx.y];
  const int C0 = cfg.C0;
  const int tid = threadIdx.x;
  const int rl = tid >> cfg.logC0;
  const int cc = tid & (C0 - 1);
  const int rpp = 256 >> cfg.logC0;
  const int nrows = M << cfg.logS;
  const double n = (double)nrows;
  const double* st = stats + cfg.statOff;
  const double mu = st[cc] / n;
  const double var = st[64 + cc] / n - mu * mu;
  const double inv = 1.0 / sqrt(var + 1e-5);
  const double g0 = (double)cfg.gb0[cc], b0 = (double)cfg.gb0[C0 + cc];
  const float sc = (float)(inv * g0);
  const float sh = (float)(b0 - mu * inv * g0);
  __shared__ float a0[256];
  float lsum = 0.f, lsq = 0.f;
  const int chunks = nrows >> (8 - cfg.logC0);
  const float* w1 = cfg.W1 + cc;
  for (int ch = blockIdx.x; ch < chunks; ch += gridDim.x) {
    const int row = ch * rpp + rl;
    const int m = row >> cfg.logS;
    const bool emp = emptybuf[cfg.emptyOff + m] != 0;
    const float h = h0_elem(cfg, kp, idxbuf, row, cc, emp);
    a0[tid] = fmaxf(h * sc + sh, 0.f);
    __syncthreads();
    float h1 = 0.f;
    const float* ar = a0 + (tid - cc);
    for (int ci = 0; ci < C0; ++ci) h1 += ar[ci] * w1[(size_t)ci * C0];
    lsum += h1; lsq += h1 * h1;
    __syncthreads();
  }
  stat_reduce(lsum, lsq, C0, cc, stats + cfg.statOff + 128, stats + cfg.statOff + 192);
}

__global__ __launch_bounds__(256) void k_final(AllCfg cfgs, const float* __restrict__ kp,
                                               const unsigned short* __restrict__ idxbuf,
                                               const int* __restrict__ emptybuf,
                                               const double* __restrict__ stats,
                                               float* __restrict__ fused) {
  const Cfg cfg = cfgs.c[blockIdx.y];
  const int C0 = cfg.C0, S = cfg.S;
  const int m = blockIdx.x;
  const int tid = threadIdx.x;
  const int cc = tid & (C0 - 1);
  const int nrows = M << cfg.logS;
  const double n = (double)nrows;
  const double* st = stats + cfg.statOff;
  const double mu0 = st[cc] / n;
  const double v0 = st[64 + cc] / n - mu0 * mu0;
  const double i0 = 1.0 / sqrt(v0 + 1e-5);
  const double g0 = (double)cfg.gb0[cc], b0 = (double)cfg.gb0[C0 + cc];
  const float sc0 = (float)(i0 * g0), sh0 = (float)(b0 - mu0 * i0 * g0);
  const double mu1 = st[128 + cc] / n;
  const double v1 = st[192 + cc] / n - mu1 * mu1;
  const double i1 = 1.0 / sqrt(v1 + 1e-5);
  const double g1 = (double)cfg.gb1[cc], b1 = (double)cfg.gb1[C0 + cc];
  const float sc1 = (float)(i1 * g1), sh1 = (float)(b1 - mu1 * i1 * g1);

  __shared__ float a0[2048];
  __shared__ float mx[64];
  if (tid < 64) mx[tid] = 0.f;
  const bool emp = emptybuf[cfg.emptyOff + m] != 0;
  const int elems = S << cfg.logC0;
  for (int e = tid; e < elems; e += 256) {
    const int s = e >> cfg.logC0;
    const int row = (m << cfg.logS) + s;
    const float h = h0_elem(cfg, kp, idxbuf, row, cc, emp);
    a0[e] = fmaxf(h * sc0 + sh0, 0.f);
  }
  __syncthreads();
  const float* w1 = cfg.W1 + cc;
  for (int e = tid; e < elems; e += 256) {
    const float* ar = a0 + (e - cc);
    float h1 = 0.f;
    for (int ci = 0; ci < C0; ++ci) h1 += ar[ci] * w1[(size_t)ci * C0];
    const float a1v = fmaxf(h1 * sc1 + sh1, 0.f);
    atomicMax((int*)&mx[cc], __float_as_int(a1v));
  }
  __syncthreads();
  if (tid < C0) fused[(size_t)m * 512 + cfg.colOff + tid] = mx[tid];
}

// ---------------------------------------------------------------------------
// BEV bilinear interpolation -> fused cols [0,128)
// ---------------------------------------------------------------------------
__global__ __launch_bounds__(256) void k_bev(const float* __restrict__ kp,
                                             const float* __restrict__ bev,
                                             float* __restrict__ fused) {
  const int e = blockIdx.x * 256 + threadIdx.x;  // 2048*128
  const int c = e & 127, m = e >> 7;
  float x, y;
  {
    #pragma clang fp contract(off)
    x = ((kp[m * 3 + 0] - (-25.6f)) / 0.1f) / 8.0f;
    y = ((kp[m * 3 + 1] - (-25.6f)) / 0.1f) / 8.0f;
  }
  const int x0 = (int)floorf(x), y0 = (int)floorf(y);
  const int x1 = x0 + 1, y1 = y0 + 1;
  const int x0c = min(max(x0, 0), 63), x1c = min(max(x1, 0), 63);
  const int y0c = min(max(y0, 0), 63), y1c = min(max(y1, 0), 63);
  float wa, wb, wc, wd;
  {
    #pragma clang fp contract(off)
    wa = ((float)x1c - x) * ((float)y1c - y);
    wb = ((float)x1c - x) * (y - (float)y0c);
    wc = (x - (float)x0c) * ((float)y1c - y);
    wd = (x - (float)x0c) * (y - (float)y0c);
  }
  const float Ia = bev[((y0c << 6) + x0c) * 128 + c];
  const float Ib = bev[((y1c << 6) + x0c) * 128 + c];
  const float Ic = bev[((y0c << 6) + x1c) * 128 + c];
  const float Id = bev[((y1c << 6) + x1c) * 128 + c];
  {
    #pragma clang fp contract(off)
    fused[(size_t)m * 512 + c] = Ia * wa + Ib * wb + Ic * wc + Id * wd;
  }
}

// ---------------------------------------------------------------------------
// Fusion: h = fused[2048,512] @ fus_W[512,32], stats over M
// ---------------------------------------------------------------------------
__global__ __launch_bounds__(256) void k_fus_mm(const float* __restrict__ fused,
                                               const float* __restrict__ fusW,
                                               float* __restrict__ hbuf,
                                               double* __restrict__ stats) {
  const int e = blockIdx.x * 256 + threadIdx.x;  // 65536
  const int k = e & 31;
  const int m = e >> 5;
  const float* fr = fused + (size_t)m * 512;
  const float* w = fusW + k;
  float h = 0.f;
  for (int c = 0; c < 512; ++c) h += fr[c] * w[(size_t)c * 32];
  hbuf[e] = h;
  stat_reduce(h, h * h, 32, k, stats + 2560, stats + 2560 + 32);
}

__global__ __launch_bounds__(256) void k_fus_out(const float* __restrict__ hbuf,
                                                 const double* __restrict__ stats,
                                                 const float* __restrict__ fgb,
                                                 float* __restrict__ out) {
  const int e = blockIdx.x * 256 + threadIdx.x;
  const int k = e & 31;
  const double n = 2048.0;
  const double* st = stats + 2560;
  const double mu = st[k] / n;
  const double v = st[32 + k] / n - mu * mu;
  const double inv = 1.0 / sqrt(v + 1e-5);
  const double g = (double)fgb[k], b = (double)fgb[32 + k];
  out[e] = fmaxf((float)(inv * g) * hbuf[e] + (float)(b - mu * inv * g), 0.f);
}

// ---------------------------------------------------------------------------
extern "C" void kernel_launch(void* const* d_in, const int* in_sizes, int n_in,
                              void* d_out, int out_size, void* d_ws, size_t ws_size,
                              hipStream_t stream) {
  (void)in_sizes; (void)n_in; (void)out_size;

  const float* kp   = (const float*)d_in[0];
  const float* raw  = (const float*)d_in[1];
  const float* bev  = (const float*)d_in[2];
  const float* c1x  = (const float*)d_in[3];
  const float* c1f  = (const float*)d_in[4];
  const float* c2x  = (const float*)d_in[5];
  const float* c2f  = (const float*)d_in[6];
  const float* c3x  = (const float*)d_in[7];
  const float* c3f  = (const float*)d_in[8];
  const float* c4x  = (const float*)d_in[9];
  const float* c4f  = (const float*)d_in[10];
  const float* fusW = (const float*)d_in[31];
  const float* fgb  = (const float*)d_in[32];

  // ws layout
  char* ws = (char*)d_ws;
  double* stats = (double*)ws;                                  // 2624 doubles
  unsigned short* idxbuf = (unsigned short*)(ws + 32768);       // 10*65536 ushort
  int* emptybuf = (int*)(ws + 32768 + 1310720);                 // 10*2048 int
  float* fused  = (float*)(ws + 1425408);                       // 2048*512 f32
  float* hbuf   = (float*)(ws + 1425408 + 4194304);             // 2048*32 f32
  float* maxbuf = (float*)(ws + 5881856);                       // 786432 f32
  float* minbuf = (float*)(ws + 9027584);                       // 786432 f32
  const size_t need_old = 5881856;
  const size_t need_new = 12173312;
  if (ws_size < need_old) return;
  const bool fast = (ws_size >= need_new);

  AllCfg cfgs;
  int mmCum = 0;
  auto setCfg = [&](int i, const float* xyz, const float* feat, int N, int Cf, int C0, int S,
                    double r, const float* W0b, const float* W1b, const float* g0b,
                    const float* g1b, int sIdx, int col) {
    Cfg& c = cfgs.c[i];
    const int Cin = 3 + Cf;
    c.xyz = xyz; c.feat = feat;
    c.W0 = W0b + (size_t)sIdx * Cin * C0;
    c.W1 = W1b + (size_t)sIdx * C0 * C0;
    c.gb0 = g0b + (size_t)sIdx * 2 * C0;
    c.gb1 = g1b + (size_t)sIdx * 2 * C0;
    c.N = N; c.S = S; c.Cfeat = Cf; c.C0 = C0;
    c.logS = (S == 16) ? 4 : 5;
    c.logC0 = (C0 == 16) ? 4 : ((C0 == 32) ? 5 : 6);
    c.colOff = col;
    c.idxOff = i * 65536;
    c.emptyOff = i * 2048;
    c.statOff = i * 256;
    c.mmOff = mmCum;
    mmCum += 2048 * C0;
    c.r2 = (float)(r * r);
  };

  const float* rW0 = (const float*)d_in[11]; const float* rW1 = (const float*)d_in[12];
  const float* rg0 = (const float*)d_in[13]; const float* rg1 = (const float*)d_in[14];
  const float* aW0 = (const float*)d_in[15]; const float* aW1 = (const float*)d_in[16];
  const float* ag0 = (const float*)d_in[17]; const float* ag1 = (const float*)d_in[18];
  const float* bW0 = (const float*)d_in[19]; const float* bW1 = (const float*)d_in[20];
  const float* bg0 = (const float*)d_in[21]; const float* bg1 = (const float*)d_in[22];
  const float* cW0 = (const float*)d_in[23]; const float* cW1 = (const float*)d_in[24];
  const float* cg0 = (const float*)d_in[25]; const float* cg1 = (const float*)d_in[26];
  const float* dW0 = (const float*)d_in[27]; const float* dW1 = (const float*)d_in[28];
  const float* dg0 = (const float*)d_in[29]; const float* dg1 = (const float*)d_in[30];

  setCfg(0, raw, nullptr, 30000,  0, 16, 16, 0.4, rW0, rW1, rg0, rg1, 0, 128);
  setCfg(1, raw, nullptr, 30000,  0, 16, 16, 0.8, rW0, rW1, rg0, rg1, 1, 144);
  setCfg(2, c1x, c1f,     30000, 16, 16, 16, 0.4, aW0, aW1, ag0, ag1, 0, 160);
  setCfg(3, c1x, c1f,     30000, 16, 16, 16, 0.8, aW0, aW1, ag0, ag1, 1, 176);
  setCfg(4, c2x, c2f,     16000, 32, 32, 16, 0.8, bW0, bW1, bg0, bg1, 0, 192);
  setCfg(5, c2x, c2f,     16000, 32, 32, 32, 1.2, bW0, bW1, bg0, bg1, 1, 224);
  setCfg(6, c3x, c3f,      8000, 64, 64, 16, 1.2, cW0, cW1, cg0, cg1, 0, 256);
  setCfg(7, c3x, c3f,      8000, 64, 64, 32, 2.4, cW0, cW1, cg0, cg1, 1, 320);
  setCfg(8, c4x, c4f,      4000, 64, 64, 16, 2.4, dW0, dW1, dg0, dg1, 0, 384);
  setCfg(9, c4x, c4f,      4000, 64, 64, 32, 4.8, dW0, dW1, dg0, dg1, 1, 448);

  hipMemsetAsync(stats, 0, 2624 * sizeof(double), stream);
  k_bev<<<dim3(1024), 256, 0, stream>>>(kp, bev, fused);
  k_ballq<<<dim3(512, 10), 256, 0, stream>>>(cfgs, kp, idxbuf, emptybuf);
  if (fast) {
    k_p1_all<<<dim3(1024, 10), 256, 0, stream>>>(cfgs, kp, idxbuf, emptybuf, stats);
    k_p2_all<<<dim3(1024, 10), 256, 0, stream>>>(cfgs, kp, idxbuf, emptybuf, stats, maxbuf, minbuf);
    k_fin<<<dim3(512, 10), 256, 0, stream>>>(cfgs, stats, maxbuf, minbuf, fused);
  } else {
    k_stats0<<<dim3(256, 10), 256, 0, stream>>>(cfgs, kp, idxbuf, emptybuf, stats);
    k_stats1<<<dim3(512, 10), 256, 0, stream>>>(cfgs, kp, idxbuf, emptybuf, stats);
    k_final<<<dim3(2048, 10), 256, 0, stream>>>(cfgs, kp, idxbuf, emptybuf, stats, fused);
  }
  k_fus_mm<<<dim3(256), 256, 0, stream>>>(fused, fusW, hbuf, stats);
  k_fus_out<<<dim3(256), 256, 0, stream>>>(hbuf, stats, fgb, (float*)d_out);
}

// Round 3
// 502.100 us; speedup vs baseline: 3.2108x; 1.0841x over previous
//
#include <hip/hip_runtime.h>
#include <math.h>

#define DEV_INLINE __device__ __forceinline__

// ---------------------------------------------------------------------------
// Config for one (point-cloud, radius-scale) SA computation. 10 total.
// ---------------------------------------------------------------------------
struct Cfg {
  const float* xyz;    // [N,3]
  const float* feat;   // [N,Cfeat] or null
  const float* W0;     // [Cin=3+Cfeat, C0] (already offset for scale)
  const float* W1;     // [C0, C0]
  const float* gb0;    // gamma at [0..C0), beta at [C0..2C0)
  const float* gb1;
  int N, S, Cfeat, C0;
  int logS, logC0;
  int colOff;          // column offset in fused [2048,512]
  int idxOff;          // offset into ushort idx buffer
  int emptyOff;        // offset into int empty buffer
  int statOff;         // offset into double stats buffer
  int mmOff;           // offset into max/min float buffers
  float r2;
};
struct AllCfg { Cfg c[10]; };

// Pair config: one point cloud scanned once for both radius scales.
struct PairCfg {
  int N, ptsOff;
  float r2s, r2b;
  int S0, S1;
  int idxOff0, idxOff1, emptyOff0, emptyOff1;
};
struct PairAll { PairCfg p[5]; };

struct PackCfg { const float* src; int N; int off; };
struct PackAll { PackCfg c[5]; };

static const int M = 2048;

DEV_INLINE unsigned fkey(float f) {
  unsigned u = __float_as_uint(f);
  return (u & 0x80000000u) ? ~u : (u | 0x80000000u);
}
DEV_INLINE float funkey(unsigned k) {
  return __uint_as_float((k & 0x80000000u) ? (k & 0x7fffffffu) : ~k);
}

// ---------------------------------------------------------------------------
// Pack [N,3] clouds into float4 for single-load access in ball query.
// ---------------------------------------------------------------------------
__global__ __launch_bounds__(256) void k_pack(PackAll pk, float4* __restrict__ pts4) {
  const PackCfg c = pk.c[blockIdx.y];
  const int j = blockIdx.x * 256 + threadIdx.x;
  if (j >= c.N) return;
  pts4[c.off + j] = make_float4(c.src[3 * j], c.src[3 * j + 1], c.src[3 * j + 2], 0.f);
}

// ---------------------------------------------------------------------------
// Fused ball query: 8 keypoints/wave, both radii per scan, reg-prefetch.
// ---------------------------------------------------------------------------
__global__ __launch_bounds__(256) void k_ballq2(PairAll pairs, const float* __restrict__ kp,
                                                const float4* __restrict__ pts4,
                                                unsigned short* __restrict__ idxbuf,
                                                int* __restrict__ emptybuf) {
  const PairCfg pc = pairs.p[blockIdx.y];
  const int lane = threadIdx.x & 63;
  const int wave = threadIdx.x >> 6;
  const int kbase = (blockIdx.x * 4 + wave) * 8;
  const float4* __restrict__ pts = pts4 + pc.ptsOff;
  const int N = pc.N;
  const float r2s = pc.r2s, r2b = pc.r2b;
  const int S0 = pc.S0, S1 = pc.S1;
  const unsigned long long lt = (1ull << lane) - 1ull;

  float qx[8], qy[8], qz[8];
  int cnt0[8], cnt1[8], f0[8], f1[8];
  #pragma unroll
  for (int k = 0; k < 8; ++k) {
    qx[k] = kp[(kbase + k) * 3 + 0];
    qy[k] = kp[(kbase + k) * 3 + 1];
    qz[k] = kp[(kbase + k) * 3 + 2];
    cnt0[k] = 0; cnt1[k] = 0; f0[k] = -1; f1[k] = -1;
  }

  float4 nxt = pts[lane];  // N >= 4000 always
  for (int base = 0; base < N; base += 64) {
    float4 cur = nxt;
    {
      int jn = base + 64 + lane;
      nxt = pts[jn < N ? jn : N - 1];
    }
    const int j = base + lane;
    float px = cur.x;
    if (j >= N) px = 3.0e38f;  // force out-of-radius for tail lanes
    const float py = cur.y, pz = cur.z;
    #pragma unroll
    for (int k = 0; k < 8; ++k) {
      float d2;
      {
        #pragma clang fp contract(off)
        const float dx = qx[k] - px;
        const float dy = qy[k] - py;
        const float dz = qz[k] - pz;
        d2 = (dx * dx + dy * dy) + dz * dz;
      }
      const bool in1 = d2 < r2b;
      const unsigned long long m1 = __ballot(in1);
      if (m1) {
        const bool in0 = d2 < r2s;
        const unsigned long long m0 = __ballot(in0);
        if (m0) {
          if (in0) {
            const int pos = cnt0[k] + __popcll(m0 & lt);
            if (pos < S0) idxbuf[pc.idxOff0 + (kbase + k) * S0 + pos] = (unsigned short)j;
          }
          if (f0[k] < 0) f0[k] = base + __builtin_ctzll(m0);
          cnt0[k] += __popcll(m0);
        }
        if (in1) {
          const int pos = cnt1[k] + __popcll(m1 & lt);
          if (pos < S1) idxbuf[pc.idxOff1 + (kbase + k) * S1 + pos] = (unsigned short)j;
        }
        if (f1[k] < 0) f1[k] = base + __builtin_ctzll(m1);
        cnt1[k] += __popcll(m1);
      }
    }
    if (((base >> 6) & 3) == 3) {
      bool done = true;
      #pragma unroll
      for (int k = 0; k < 8; ++k) done = done && (cnt0[k] >= S0) && (cnt1[k] >= S1);
      if (done) break;
    }
  }

  #pragma unroll
  for (int k = 0; k < 8; ++k) {
    const unsigned short fv0 = (unsigned short)(f0[k] < 0 ? 0 : f0[k]);
    for (int p = cnt0[k] + lane; p < S0; p += 64)
      idxbuf[pc.idxOff0 + (kbase + k) * S0 + p] = fv0;
    const unsigned short fv1 = (unsigned short)(f1[k] < 0 ? 0 : f1[k]);
    for (int p = cnt1[k] + lane; p < S1; p += 64)
      idxbuf[pc.idxOff1 + (kbase + k) * S1 + p] = fv1;
    if (lane == 0) {
      emptybuf[pc.emptyOff0 + kbase + k] = (f0[k] < 0) ? 1 : 0;
      emptybuf[pc.emptyOff1 + kbase + k] = (f1[k] < 0) ? 1 : 0;
    }
  }
}

// ---------------------------------------------------------------------------
// Old ball query (fallback): one wave per keypoint.
// ---------------------------------------------------------------------------
__global__ __launch_bounds__(256) void k_ballq(AllCfg cfgs, const float* __restrict__ kp,
                                               unsigned short* __restrict__ idxbuf,
                                               int* __restrict__ emptybuf) {
  const Cfg cfg = cfgs.c[blockIdx.y];
  const int lane = threadIdx.x & 63;
  const int wid = (blockIdx.x * blockDim.x + threadIdx.x) >> 6;
  if (wid >= M) return;
  const float qx = kp[wid * 3 + 0], qy = kp[wid * 3 + 1], qz = kp[wid * 3 + 2];
  const int N = cfg.N, S = cfg.S;
  const float r2 = cfg.r2;
  const float* __restrict__ xyz = cfg.xyz;
  unsigned short* out = idxbuf + cfg.idxOff + wid * S;
  int cnt = 0, first = -1;
  for (int base = 0; base < N; base += 64) {
    const int j = base + lane;
    bool inb = false;
    if (j < N) {
      #pragma clang fp contract(off)
      const float dx = qx - xyz[j * 3 + 0];
      const float dy = qy - xyz[j * 3 + 1];
      const float dz = qz - xyz[j * 3 + 2];
      const float d2 = (dx * dx + dy * dy) + dz * dz;
      inb = d2 < r2;
    }
    const unsigned long long msk = __ballot(inb);
    if (msk) {
      if (inb) {
        const int pos = cnt + __popcll(msk & ((1ull << lane) - 1ull));
        if (pos < S) out[pos] = (unsigned short)j;
      }
      if (first < 0) first = base + __builtin_ctzll(msk);
      cnt += __popcll(msk);
      if (cnt >= S) break;
    }
  }
  const unsigned short fillv = (unsigned short)(first < 0 ? 0 : first);
  for (int p = cnt + lane; p < S; p += 64) out[p] = fillv;
  if (lane == 0) emptybuf[cfg.emptyOff + wid] = (first < 0) ? 1 : 0;
}

// ---------------------------------------------------------------------------
// Shared helpers for templated tile kernels
// ---------------------------------------------------------------------------
template<int CIN, int S>
DEV_INLINE void stage_rows(const Cfg& cfg, const float* __restrict__ kp,
                           const unsigned short* __restrict__ idxbuf,
                           const int* __restrict__ emptybuf,
                           int base, float (*in_lds)[(CIN + 3) & ~3]) {
  const int tid = threadIdx.x;
  const int r = tid >> 2, j = tid & 3;
  const int grow = base + r;
  const int m = grow >> ((S == 16) ? 4 : 5);
  const bool emp = emptybuf[cfg.emptyOff + m] != 0;
  const int idx = (int)idxbuf[cfg.idxOff + grow];
  float* dst = in_lds[r];
  if (j == 0) {
    if (emp) { dst[0] = 0.f; dst[1] = 0.f; dst[2] = 0.f; }
    else {
      const float* p = cfg.xyz + 3 * idx;
      dst[0] = p[0] - kp[m * 3 + 0];
      dst[1] = p[1] - kp[m * 3 + 1];
      dst[2] = p[2] - kp[m * 3 + 2];
    }
  }
  if constexpr (CIN > 3) {
    constexpr int CF4 = (CIN - 3) / 4;
    const float4* f4 = (const float4*)cfg.feat + (size_t)idx * CF4;
    for (int c = j; c < CF4; c += 4) {
      float4 v;
      if (emp) v = make_float4(0.f, 0.f, 0.f, 0.f); else v = f4[c];
      dst[3 + 4 * c] = v.x; dst[4 + 4 * c] = v.y;
      dst[5 + 4 * c] = v.z; dst[6 + 4 * c] = v.w;
    }
  }
}

template<int CIN>
DEV_INLINE float dotw(const float* __restrict__ in, const float* __restrict__ w) {
  float h = 0.f;
  #pragma unroll
  for (int ci = 0; ci < CIN; ++ci) h += in[ci] * w[ci];
  return h;
}

DEV_INLINE void stat_reduce_s(float lsum, float lsq, int C0, int cc,
                              float* sA, float* sB, double* gsum, double* gsq) {
  __syncthreads();
  for (int off = 32; off >= C0; off >>= 1) {
    lsum += __shfl_xor(lsum, off);
    lsq  += __shfl_xor(lsq, off);
  }
  if (threadIdx.x < 64) { sA[threadIdx.x] = 0.f; sB[threadIdx.x] = 0.f; }
  __syncthreads();
  if ((int)(threadIdx.x & 63) < C0) { atomicAdd(&sA[cc], lsum); atomicAdd(&sB[cc], lsq); }
  __syncthreads();
  if ((int)threadIdx.x < C0) {
    atomicAdd(&gsum[threadIdx.x], (double)sA[threadIdx.x]);
    atomicAdd(&gsq[threadIdx.x],  (double)sB[threadIdx.x]);
  }
}

// ---------------------------------------------------------------------------
// P1: h0 stats. One 64-row tile per block.
// ---------------------------------------------------------------------------
template<int C0, int CIN, int S>
__device__ __forceinline__ void p1_impl(const Cfg& cfg, const float* __restrict__ kp,
                                        const unsigned short* __restrict__ idxbuf,
                                        const int* __restrict__ emptybuf,
                                        double* __restrict__ stats, char* smem) {
  if ((int)blockIdx.x >= 32 * S) return;
  constexpr int CP = (CIN + 3) & ~3;
  constexpr int STEP = 256 / C0;
  constexpr int RPT = 64 / STEP;
  constexpr int LOGC0 = (C0 == 16) ? 4 : ((C0 == 32) ? 5 : 6);
  float (*in_lds)[CP] = (float(*)[CP])smem;
  const int tid = threadIdx.x;
  const int base = blockIdx.x * 64;
  stage_rows<CIN, S>(cfg, kp, idxbuf, emptybuf, base, in_lds);
  const int cc = tid & (C0 - 1);
  const int rg = tid >> LOGC0;
  float w0[CIN];
  #pragma unroll
  for (int ci = 0; ci < CIN; ++ci) w0[ci] = cfg.W0[ci * C0 + cc];
  __syncthreads();
  float lsum = 0.f, lsq = 0.f;
  for (int rr = 0; rr < RPT; ++rr) {
    const float h = dotw<CIN>(in_lds[rg + rr * STEP], w0);
    lsum += h; lsq += h * h;
  }
  stat_reduce_s(lsum, lsq, C0, cc, (float*)smem, (float*)smem + 64,
                stats + cfg.statOff, stats + cfg.statOff + 64);
}

__global__ __launch_bounds__(256) void k_p1_all(AllCfg cfgs, const float* __restrict__ kp,
                                                const unsigned short* __restrict__ idxbuf,
                                                const int* __restrict__ emptybuf,
                                                double* __restrict__ stats) {
  __shared__ char smem[18432];
  switch (blockIdx.y) {
    case 0: p1_impl<16, 3, 16>(cfgs.c[0], kp, idxbuf, emptybuf, stats, smem); break;
    case 1: p1_impl<16, 3, 16>(cfgs.c[1], kp, idxbuf, emptybuf, stats, smem); break;
    case 2: p1_impl<16, 19, 16>(cfgs.c[2], kp, idxbuf, emptybuf, stats, smem); break;
    case 3: p1_impl<16, 19, 16>(cfgs.c[3], kp, idxbuf, emptybuf, stats, smem); break;
    case 4: p1_impl<32, 35, 16>(cfgs.c[4], kp, idxbuf, emptybuf, stats, smem); break;
    case 5: p1_impl<32, 35, 32>(cfgs.c[5], kp, idxbuf, emptybuf, stats, smem); break;
    case 6: p1_impl<64, 67, 16>(cfgs.c[6], kp, idxbuf, emptybuf, stats, smem); break;
    case 7: p1_impl<64, 67, 32>(cfgs.c[7], kp, idxbuf, emptybuf, stats, smem); break;
    case 8: p1_impl<64, 67, 16>(cfgs.c[8], kp, idxbuf, emptybuf, stats, smem); break;
    case 9: p1_impl<64, 67, 32>(cfgs.c[9], kp, idxbuf, emptybuf, stats, smem); break;
  }
}

// ---------------------------------------------------------------------------
// P2: recompute h0 -> BN0+ReLU -> a0 (LDS) -> h1, h1 stats + per-(m,cc) max/min.
// ---------------------------------------------------------------------------
template<int C0, int CIN, int S>
__device__ __forceinline__ void p2_impl(const Cfg& cfg, const float* __restrict__ kp,
                                        const unsigned short* __restrict__ idxbuf,
                                        const int* __restrict__ emptybuf,
                                        double* __restrict__ stats,
                                        float* __restrict__ maxbuf,
                                        float* __restrict__ minbuf, char* smem) {
  if ((int)blockIdx.x >= 32 * S) return;
  constexpr int CP = (CIN + 3) & ~3;
  constexpr int STEP = 256 / C0;
  constexpr int RPT = 64 / STEP;
  constexpr int LOGC0 = (C0 == 16) ? 4 : ((C0 == 32) ? 5 : 6);
  constexpr int LOGS = (S == 16) ? 4 : 5;
  constexpr int NM = 64 / S;
  float (*in_lds)[CP] = (float(*)[CP])smem;
  float (*a0_lds)[C0] = (float(*)[C0])(smem + 64 * CP * 4);
  unsigned* mxl = (unsigned*)(smem + 64 * CP * 4 + 64 * C0 * 4);
  unsigned* mnl = mxl + NM * C0;
  const int tid = threadIdx.x;
  const int base = blockIdx.x * 64;
  stage_rows<CIN, S>(cfg, kp, idxbuf, emptybuf, base, in_lds);
  if (tid < NM * C0) { mxl[tid] = 0u; mnl[tid] = 0xFFFFFFFFu; }
  const int cc = tid & (C0 - 1);
  const int rg = tid >> LOGC0;
  float w0[CIN], w1[C0];
  #pragma unroll
  for (int ci = 0; ci < CIN; ++ci) w0[ci] = cfg.W0[ci * C0 + cc];
  #pragma unroll
  for (int ci = 0; ci < C0; ++ci) w1[ci] = cfg.W1[ci * C0 + cc];
  const double n = (double)(2048 * S);
  const double* st = stats + cfg.statOff;
  const double mu = st[cc] / n;
  const double var = st[64 + cc] / n - mu * mu;
  const double inv = 1.0 / sqrt(var + 1e-5);
  const double g0 = (double)cfg.gb0[cc], b0 = (double)cfg.gb0[C0 + cc];
  const float sc0 = (float)(inv * g0), sh0 = (float)(b0 - mu * inv * g0);
  __syncthreads();
  for (int rr = 0; rr < RPT; ++rr) {
    const int r = rg + rr * STEP;
    const float h = dotw<CIN>(in_lds[r], w0);
    a0_lds[r][cc] = fmaxf(h * sc0 + sh0, 0.f);
  }
  __syncthreads();
  float lsum = 0.f, lsq = 0.f;
  for (int rr = 0; rr < RPT; ++rr) {
    const int r = rg + rr * STEP;
    float h1 = 0.f;
    #pragma unroll
    for (int ci = 0; ci < C0; ++ci) h1 += a0_lds[r][ci] * w1[ci];
    lsum += h1; lsq += h1 * h1;
    const unsigned k = fkey(h1);
    atomicMax(&mxl[(r >> LOGS) * C0 + cc], k);
    atomicMin(&mnl[(r >> LOGS) * C0 + cc], k);
  }
  stat_reduce_s(lsum, lsq, C0, cc, (float*)in_lds, (float*)in_lds + 64,
                stats + cfg.statOff + 128, stats + cfg.statOff + 192);
  __syncthreads();
  if (tid < NM * C0) {
    const int gcell = (base >> LOGS) * C0 + tid;
    maxbuf[cfg.mmOff + gcell] = funkey(mxl[tid]);
    minbuf[cfg.mmOff + gcell] = funkey(mnl[tid]);
  }
}

__global__ __launch_bounds__(256) void k_p2_all(AllCfg cfgs, const float* __restrict__ kp,
                                                const unsigned short* __restrict__ idxbuf,
                                                const int* __restrict__ emptybuf,
                                                double* __restrict__ stats,
                                                float* __restrict__ maxbuf,
                                                float* __restrict__ minbuf) {
  __shared__ char smem[36864];
  switch (blockIdx.y) {
    case 0: p2_impl<16, 3, 16>(cfgs.c[0], kp, idxbuf, emptybuf, stats, maxbuf, minbuf, smem); break;
    case 1: p2_impl<16, 3, 16>(cfgs.c[1], kp, idxbuf, emptybuf, stats, maxbuf, minbuf, smem); break;
    case 2: p2_impl<16, 19, 16>(cfgs.c[2], kp, idxbuf, emptybuf, stats, maxbuf, minbuf, smem); break;
    case 3: p2_impl<16, 19, 16>(cfgs.c[3], kp, idxbuf, emptybuf, stats, maxbuf, minbuf, smem); break;
    case 4: p2_impl<32, 35, 16>(cfgs.c[4], kp, idxbuf, emptybuf, stats, maxbuf, minbuf, smem); break;
    case 5: p2_impl<32, 35, 32>(cfgs.c[5], kp, idxbuf, emptybuf, stats, maxbuf, minbuf, smem); break;
    case 6: p2_impl<64, 67, 16>(cfgs.c[6], kp, idxbuf, emptybuf, stats, maxbuf, minbuf, smem); break;
    case 7: p2_impl<64, 67, 32>(cfgs.c[7], kp, idxbuf, emptybuf, stats, maxbuf, minbuf, smem); break;
    case 8: p2_impl<64, 67, 16>(cfgs.c[8], kp, idxbuf, emptybuf, stats, maxbuf, minbuf, smem); break;
    case 9: p2_impl<64, 67, 32>(cfgs.c[9], kp, idxbuf, emptybuf, stats, maxbuf, minbuf, smem); break;
  }
}

// ---------------------------------------------------------------------------
// Finalize: apply folded BN1 + ReLU at the h1 extremum (monotone => exact max).
// ---------------------------------------------------------------------------
__global__ __launch_bounds__(256) void k_fin(AllCfg cfgs, const double* __restrict__ stats,
                                             const float* __restrict__ maxbuf,
                                             const float* __restrict__ minbuf,
                                             float* __restrict__ fused) {
  const Cfg cfg = cfgs.c[blockIdx.y];
  const int C0 = cfg.C0;
  const int e = blockIdx.x * 256 + threadIdx.x;
  if (e >= 2048 * C0) return;
  const int cc = e & (C0 - 1);
  const int m = e >> cfg.logC0;
  const double n = (double)(2048 * cfg.S);
  const double* st = stats + cfg.statOff;
  const double mu = st[128 + cc] / n;
  const double v = st[192 + cc] / n - mu * mu;
  const double inv = 1.0 / sqrt(v + 1e-5);
  const double g = (double)cfg.gb1[cc], b = (double)cfg.gb1[C0 + cc];
  const float sc = (float)(inv * g), sh = (float)(b - mu * inv * g);
  const float x = (sc >= 0.f) ? maxbuf[cfg.mmOff + e] : minbuf[cfg.mmOff + e];
  fused[(size_t)m * 512 + cfg.colOff + cc] = fmaxf(sc * x + sh, 0.f);
}

// ---------------------------------------------------------------------------
// Old path (fallback when ws too small): stats0/stats1/final recompute chain.
// ---------------------------------------------------------------------------
DEV_INLINE float h0_elem(const Cfg& cfg, const float* __restrict__ kp,
                         const unsigned short* __restrict__ idxbuf,
                         int row, int co, bool emp) {
  if (emp) return 0.f;
  const int m = row >> cfg.logS;
  const int idx = (int)idxbuf[cfg.idxOff + row];
  const float* p = cfg.xyz + 3 * idx;
  const float gx = p[0] - kp[m * 3 + 0];
  const float gy = p[1] - kp[m * 3 + 1];
  const float gz = p[2] - kp[m * 3 + 2];
  const int C0 = cfg.C0;
  const float* w = cfg.W0 + co;
  float h = gx * w[0] + gy * w[C0] + gz * w[2 * C0];
  const float* f = cfg.feat + (size_t)idx * cfg.Cfeat;
  for (int ci = 0; ci < cfg.Cfeat; ++ci) h += f[ci] * w[(size_t)(3 + ci) * C0];
  return h;
}

DEV_INLINE void stat_reduce(float lsum, float lsq, int C0, int cc,
                            double* gsum, double* gsq) {
  for (int off = 32; off >= C0; off >>= 1) {
    lsum += __shfl_xor(lsum, off);
    lsq  += __shfl_xor(lsq, off);
  }
  __shared__ float sA[64], sB[64];
  if (threadIdx.x < 64) { sA[threadIdx.x] = 0.f; sB[threadIdx.x] = 0.f; }
  __syncthreads();
  if ((int)(threadIdx.x & 63) < C0) { atomicAdd(&sA[cc], lsum); atomicAdd(&sB[cc], lsq); }
  __syncthreads();
  if ((int)threadIdx.x < C0) {
    atomicAdd(&gsum[threadIdx.x], (double)sA[threadIdx.x]);
    atomicAdd(&gsq[threadIdx.x],  (double)sB[threadIdx.x]);
  }
}

__global__ __launch_bounds__(256) void k_stats0(AllCfg cfgs, const float* __restrict__ kp,
                                                const unsigned short* __restrict__ idxbuf,
                                                const int* __restrict__ emptybuf,
                                                double* __restrict__ stats) {
  const Cfg cfg = cfgs.c[blockIdx.y];
  const int C0 = cfg.C0;
  const int total = (M << cfg.logS) << cfg.logC0;
  const int stride = gridDim.x * 256;
  const int t0 = blockIdx.x * 256 + threadIdx.x;
  const int cc = t0 & (C0 - 1);
  float lsum = 0.f, lsq = 0.f;
  for (int e = t0; e < total; e += stride) {
    const int row = e >> cfg.logC0;
    const int m = row >> cfg.logS;
    const bool emp = emptybuf[cfg.emptyOff + m] != 0;
    const float h = h0_elem(cfg, kp, idxbuf, row, cc, emp);
    lsum += h; lsq += h * h;
  }
  stat_reduce(lsum, lsq, C0, cc, stats + cfg.statOff, stats + cfg.statOff + 64);
}

__global__ __launch_bounds__(256) void k_stats1(AllCfg cfgs, const float* __restrict__ kp,
                                                const unsigned short* __restrict__ idxbuf,
                                                const int* __restrict__ emptybuf,
                                                double* __restrict__ stats) {
  const Cfg cfg = cfgs.c[blockIdx.y];
  const int C0 = cfg.C0;
  const int tid = threadIdx.x;
  const int rl = tid >> cfg.logC0;
  const int cc = tid & (C0 - 1);
  const int rpp = 256 >> cfg.logC0;
  const int nrows = M << cfg.logS;
  const double n = (double)nrows;
  const double* st = stats + cfg.statOff;
  const double mu = st[cc] / n;
  const double var = st[64 + cc] / n - mu * mu;
  const double inv = 1.0 / sqrt(var + 1e-5);
  const double g0 = (double)cfg.gb0[cc], b0 = (double)cfg.gb0[C0 + cc];
  const float sc = (float)(inv * g0);
  const float sh = (float)(b0 - mu * inv * g0);
  __shared__ float a0[256];
  float lsum = 0.f, lsq = 0.f;
  const int chunks = nrows >> (8 - cfg.logC0);
  const float* w1 = cfg.W1 + cc;
  for (int ch = blockIdx.x; ch < chunks; ch += gridDim.x) {
    const int row = ch * rpp + rl;
    const int m = row >> cfg.logS;
    const bool emp = emptybuf[cfg.emptyOff + m] != 0;
    const float h = h0_elem(cfg, kp, idxbuf, row, cc, emp);
    a0[tid] = fmaxf(h * sc + sh, 0.f);
    __syncthreads();
    float h1 = 0.f;
    const float* ar = a0 + (tid - cc);
    for (int ci = 0; ci < C0; ++ci) h1 += ar[ci] * w1[(size_t)ci * C0];
    lsum += h1; lsq += h1 * h1;
    __syncthreads();
  }
  stat_reduce(lsum, lsq, C0, cc, stats + cfg.statOff + 128, stats + cfg.statOff + 192);
}

__global__ __launch_bounds__(256) void k_final(AllCfg cfgs, const float* __restrict__ kp,
                                               const unsigned short* __restrict__ idxbuf,
                                               const int* __restrict__ emptybuf,
                                               const double* __restrict__ stats,
                                               float* __restrict__ fused) {
  const Cfg cfg = cfgs.c[blockIdx.y];
  const int C0 = cfg.C0, S = cfg.S;
  const int m = blockIdx.x;
  const int tid = threadIdx.x;
  const int cc = tid & (C0 - 1);
  const int nrows = M << cfg.logS;
  const double n = (double)nrows;
  const double* st = stats + cfg.statOff;
  const double mu0 = st[cc] / n;
  const double v0 = st[64 + cc] / n - mu0 * mu0;
  const double i0 = 1.0 / sqrt(v0 + 1e-5);
  const double g0 = (double)cfg.gb0[cc], b0 = (double)cfg.gb0[C0 + cc];
  const float sc0 = (float)(i0 * g0), sh0 = (float)(b0 - mu0 * i0 * g0);
  const double mu1 = st[128 + cc] / n;
  const double v1 = st[192 + cc] / n - mu1 * mu1;
  const double i1 = 1.0 / sqrt(v1 + 1e-5);
  const double g1 = (double)cfg.gb1[cc], b1 = (double)cfg.gb1[C0 + cc];
  const float sc1 = (float)(i1 * g1), sh1 = (float)(b1 - mu1 * i1 * g1);

  __shared__ float a0[2048];
  __shared__ float mx[64];
  if (tid < 64) mx[tid] = 0.f;
  const bool emp = emptybuf[cfg.emptyOff + m] != 0;
  const int elems = S << cfg.logC0;
  for (int e = tid; e < elems; e += 256) {
    const int s = e >> cfg.logC0;
    const int row = (m << cfg.logS) + s;
    const float h = h0_elem(cfg, kp, idxbuf, row, cc, emp);
    a0[e] = fmaxf(h * sc0 + sh0, 0.f);
  }
  __syncthreads();
  const float* w1 = cfg.W1 + cc;
  for (int e = tid; e < elems; e += 256) {
    const float* ar = a0 + (e - cc);
    float h1 = 0.f;
    for (int ci = 0; ci < C0; ++ci) h1 += ar[ci] * w1[(size_t)ci * C0];
    const float a1v = fmaxf(h1 * sc1 + sh1, 0.f);
    atomicMax((int*)&mx[cc], __float_as_int(a1v));
  }
  __syncthreads();
  if (tid < C0) fused[(size_t)m * 512 + cfg.colOff + tid] = mx[tid];
}

// ---------------------------------------------------------------------------
// BEV bilinear interpolation -> fused cols [0,128)
// ---------------------------------------------------------------------------
__global__ __launch_bounds__(256) void k_bev(const float* __restrict__ kp,
                                             const float* __restrict__ bev,
                                             float* __restrict__ fused) {
  const int e = blockIdx.x * 256 + threadIdx.x;  // 2048*128
  const int c = e & 127, m = e >> 7;
  float x, y;
  {
    #pragma clang fp contract(off)
    x = ((kp[m * 3 + 0] - (-25.6f)) / 0.1f) / 8.0f;
    y = ((kp[m * 3 + 1] - (-25.6f)) / 0.1f) / 8.0f;
  }
  const int x0 = (int)floorf(x), y0 = (int)floorf(y);
  const int x1 = x0 + 1, y1 = y0 + 1;
  const int x0c = min(max(x0, 0), 63), x1c = min(max(x1, 0), 63);
  const int y0c = min(max(y0, 0), 63), y1c = min(max(y1, 0), 63);
  float wa, wb, wc, wd;
  {
    #pragma clang fp contract(off)
    wa = ((float)x1c - x) * ((float)y1c - y);
    wb = ((float)x1c - x) * (y - (float)y0c);
    wc = (x - (float)x0c) * ((float)y1c - y);
    wd = (x - (float)x0c) * (y - (float)y0c);
  }
  const float Ia = bev[((y0c << 6) + x0c) * 128 + c];
  const float Ib = bev[((y1c << 6) + x0c) * 128 + c];
  const float Ic = bev[((y0c << 6) + x1c) * 128 + c];
  const float Id = bev[((y1c << 6) + x1c) * 128 + c];
  {
    #pragma clang fp contract(off)
    fused[(size_t)m * 512 + c] = Ia * wa + Ib * wb + Ic * wc + Id * wd;
  }
}

// ---------------------------------------------------------------------------
// Fusion: h = fused[2048,512] @ fus_W[512,32], stats over M
// ---------------------------------------------------------------------------
__global__ __launch_bounds__(256) void k_fus_mm(const float* __restrict__ fused,
                                               const float* __restrict__ fusW,
                                               float* __restrict__ hbuf,
                                               double* __restrict__ stats) {
  const int e = blockIdx.x * 256 + threadIdx.x;  // 65536
  const int k = e & 31;
  const int m = e >> 5;
  const float* fr = fused + (size_t)m * 512;
  const float* w = fusW + k;
  float h = 0.f;
  for (int c = 0; c < 512; ++c) h += fr[c] * w[(size_t)c * 32];
  hbuf[e] = h;
  stat_reduce(h, h * h, 32, k, stats + 2560, stats + 2560 + 32);
}

__global__ __launch_bounds__(256) void k_fus_out(const float* __restrict__ hbuf,
                                                 const double* __restrict__ stats,
                                                 const float* __restrict__ fgb,
                                                 float* __restrict__ out) {
  const int e = blockIdx.x * 256 + threadIdx.x;
  const int k = e & 31;
  const double n = 2048.0;
  const double* st = stats + 2560;
  const double mu = st[k] / n;
  const double v = st[32 + k] / n - mu * mu;
  const double inv = 1.0 / sqrt(v + 1e-5);
  const double g = (double)fgb[k], b = (double)fgb[32 + k];
  out[e] = fmaxf((float)(inv * g) * hbuf[e] + (float)(b - mu * inv * g), 0.f);
}

// ---------------------------------------------------------------------------
extern "C" void kernel_launch(void* const* d_in, const int* in_sizes, int n_in,
                              void* d_out, int out_size, void* d_ws, size_t ws_size,
                              hipStream_t stream) {
  (void)in_sizes; (void)n_in; (void)out_size;

  const float* kp   = (const float*)d_in[0];
  const float* raw  = (const float*)d_in[1];
  const float* bev  = (const float*)d_in[2];
  const float* c1x  = (const float*)d_in[3];
  const float* c1f  = (const float*)d_in[4];
  const float* c2x  = (const float*)d_in[5];
  const float* c2f  = (const float*)d_in[6];
  const float* c3x  = (const float*)d_in[7];
  const float* c3f  = (const float*)d_in[8];
  const float* c4x  = (const float*)d_in[9];
  const float* c4f  = (const float*)d_in[10];
  const float* fusW = (const float*)d_in[31];
  const float* fgb  = (const float*)d_in[32];

  // ws layout
  char* ws = (char*)d_ws;
  double* stats = (double*)ws;                                  // 2624 doubles
  unsigned short* idxbuf = (unsigned short*)(ws + 32768);       // 10*65536 ushort
  int* emptybuf = (int*)(ws + 32768 + 1310720);                 // 10*2048 int
  float* fused  = (float*)(ws + 1425408);                       // 2048*512 f32
  float* hbuf   = (float*)(ws + 1425408 + 4194304);             // 2048*32 f32
  float* maxbuf = (float*)(ws + 5881856);                       // 786432 f32
  float* minbuf = (float*)(ws + 9027584);                       // 786432 f32
  float4* pts4  = (float4*)(ws + 12173312);                     // 88000 float4
  const size_t need_old = 5881856;
  const size_t need_new = 12173312;
  const size_t need_bq2 = 12173312 + 1408000;
  if (ws_size < need_old) return;
  const bool fast = (ws_size >= need_new);
  const bool bq2 = (ws_size >= need_bq2);

  AllCfg cfgs;
  int mmCum = 0;
  auto setCfg = [&](int i, const float* xyz, const float* feat, int N, int Cf, int C0, int S,
                    double r, const float* W0b, const float* W1b, const float* g0b,
                    const float* g1b, int sIdx, int col) {
    Cfg& c = cfgs.c[i];
    const int Cin = 3 + Cf;
    c.xyz = xyz; c.feat = feat;
    c.W0 = W0b + (size_t)sIdx * Cin * C0;
    c.W1 = W1b + (size_t)sIdx * C0 * C0;
    c.gb0 = g0b + (size_t)sIdx * 2 * C0;
    c.gb1 = g1b + (size_t)sIdx * 2 * C0;
    c.N = N; c.S = S; c.Cfeat = Cf; c.C0 = C0;
    c.logS = (S == 16) ? 4 : 5;
    c.logC0 = (C0 == 16) ? 4 : ((C0 == 32) ? 5 : 6);
    c.colOff = col;
    c.idxOff = i * 65536;
    c.emptyOff = i * 2048;
    c.statOff = i * 256;
    c.mmOff = mmCum;
    mmCum += 2048 * C0;
    c.r2 = (float)(r * r);
  };

  const float* rW0 = (const float*)d_in[11]; const float* rW1 = (const float*)d_in[12];
  const float* rg0 = (const float*)d_in[13]; const float* rg1 = (const float*)d_in[14];
  const float* aW0 = (const float*)d_in[15]; const float* aW1 = (const float*)d_in[16];
  const float* ag0 = (const float*)d_in[17]; const float* ag1 = (const float*)d_in[18];
  const float* bW0 = (const float*)d_in[19]; const float* bW1 = (const float*)d_in[20];
  const float* bg0 = (const float*)d_in[21]; const float* bg1 = (const float*)d_in[22];
  const float* cW0 = (const float*)d_in[23]; const float* cW1 = (const float*)d_in[24];
  const float* cg0 = (const float*)d_in[25]; const float* cg1 = (const float*)d_in[26];
  const float* dW0 = (const float*)d_in[27]; const float* dW1 = (const float*)d_in[28];
  const float* dg0 = (const float*)d_in[29]; const float* dg1 = (const float*)d_in[30];

  setCfg(0, raw, nullptr, 30000,  0, 16, 16, 0.4, rW0, rW1, rg0, rg1, 0, 128);
  setCfg(1, raw, nullptr, 30000,  0, 16, 16, 0.8, rW0, rW1, rg0, rg1, 1, 144);
  setCfg(2, c1x, c1f,     30000, 16, 16, 16, 0.4, aW0, aW1, ag0, ag1, 0, 160);
  setCfg(3, c1x, c1f,     30000, 16, 16, 16, 0.8, aW0, aW1, ag0, ag1, 1, 176);
  setCfg(4, c2x, c2f,     16000, 32, 32, 16, 0.8, bW0, bW1, bg0, bg1, 0, 192);
  setCfg(5, c2x, c2f,     16000, 32, 32, 32, 1.2, bW0, bW1, bg0, bg1, 1, 224);
  setCfg(6, c3x, c3f,      8000, 64, 64, 16, 1.2, cW0, cW1, cg0, cg1, 0, 256);
  setCfg(7, c3x, c3f,      8000, 64, 64, 32, 2.4, cW0, cW1, cg0, cg1, 1, 320);
  setCfg(8, c4x, c4f,      4000, 64, 64, 16, 2.4, dW0, dW1, dg0, dg1, 0, 384);
  setCfg(9, c4x, c4f,      4000, 64, 64, 32, 4.8, dW0, dW1, dg0, dg1, 1, 448);

  hipMemsetAsync(stats, 0, 2624 * sizeof(double), stream);

  if (bq2) {
    PackAll pk;
    pk.c[0] = { raw, 30000, 0 };
    pk.c[1] = { c1x, 30000, 30000 };
    pk.c[2] = { c2x, 16000, 60000 };
    pk.c[3] = { c3x,  8000, 76000 };
    pk.c[4] = { c4x,  4000, 84000 };
    PairAll pr;
    auto setPair = [&](int p, int ci0, int ci1, int N, int off) {
      PairCfg& q = pr.p[p];
      q.N = N; q.ptsOff = off;
      q.r2s = cfgs.c[ci0].r2; q.r2b = cfgs.c[ci1].r2;
      q.S0 = cfgs.c[ci0].S;   q.S1 = cfgs.c[ci1].S;
      q.idxOff0 = cfgs.c[ci0].idxOff;     q.idxOff1 = cfgs.c[ci1].idxOff;
      q.emptyOff0 = cfgs.c[ci0].emptyOff; q.emptyOff1 = cfgs.c[ci1].emptyOff;
    };
    setPair(0, 0, 1, 30000, 0);
    setPair(1, 2, 3, 30000, 30000);
    setPair(2, 4, 5, 16000, 60000);
    setPair(3, 6, 7,  8000, 76000);
    setPair(4, 8, 9,  4000, 84000);
    k_pack<<<dim3(118, 5), 256, 0, stream>>>(pk, pts4);
    k_ballq2<<<dim3(64, 5), 256, 0, stream>>>(pr, kp, pts4, idxbuf, emptybuf);
  } else {
    k_ballq<<<dim3(512, 10), 256, 0, stream>>>(cfgs, kp, idxbuf, emptybuf);
  }

  k_bev<<<dim3(1024), 256, 0, stream>>>(kp, bev, fused);
  if (fast) {
    k_p1_all<<<dim3(1024, 10), 256, 0, stream>>>(cfgs, kp, idxbuf, emptybuf, stats);
    k_p2_all<<<dim3(1024, 10), 256, 0, stream>>>(cfgs, kp, idxbuf, emptybuf, stats, maxbuf, minbuf);
    k_fin<<<dim3(512, 10), 256, 0, stream>>>(cfgs, stats, maxbuf, minbuf, fused);
  } else {
    k_stats0<<<dim3(256, 10), 256, 0, stream>>>(cfgs, kp, idxbuf, emptybuf, stats);
    k_stats1<<<dim3(512, 10), 256, 0, stream>>>(cfgs, kp, idxbuf, emptybuf, stats);
    k_final<<<dim3(2048, 10), 256, 0, stream>>>(cfgs, kp, idxbuf, emptybuf, stats, fused);
  }
  k_fus_mm<<<dim3(256), 256, 0, stream>>>(fused, fusW, hbuf, stats);
  k_fus_out<<<dim3(256), 256, 0, stream>>>(hbuf, stats, fgb, (float*)d_out);
}

// Round 4
// 400.507 us; speedup vs baseline: 4.0252x; 1.2537x over previous
//
#include <hip/hip_runtime.h>
#include <math.h>

#define DEV_INLINE __device__ __forceinline__

// ---------------------------------------------------------------------------
// Config for one (point-cloud, radius-scale) SA computation. 10 total.
// ---------------------------------------------------------------------------
struct Cfg {
  const float* xyz;    // [N,3]
  const float* feat;   // [N,Cfeat] or null
  const float* W0;     // [Cin=3+Cfeat, C0] (already offset for scale)
  const float* W1;     // [C0, C0]
  const float* gb0;    // gamma at [0..C0), beta at [C0..2C0)
  const float* gb1;
  int N, S, Cfeat, C0;
  int logS, logC0;
  int colOff;          // column offset in fused [2048,512]
  int idxOff;          // offset into ushort idx buffer (final, merged)
  int emptyOff;        // offset into int empty buffer
  int statOff;         // offset into double stats buffer
  int mmOff;           // offset into max/min float buffers
  int hIdxOff;         // offset into half-idx ushort buffer ([2][2048][S])
  float r2;
};
struct AllCfg { Cfg c[10]; };

// Pair config: one point cloud scanned once for both radius scales, split scan.
struct PairCfg {
  int N, ptsOff;
  float r2s, r2b;
  int S0, S1;
  int hIdxOff0, hIdxOff1;  // into half-idx ushort buffer
  int ci0, ci1;            // cfg indices (for cnt buffer)
};
struct PairAll { PairCfg p[5]; };

struct PackCfg { const float* src; int N; int off; };
struct PackAll { PackCfg c[5]; };

static const int M = 2048;

DEV_INLINE unsigned fkey(float f) {
  unsigned u = __float_as_uint(f);
  return (u & 0x80000000u) ? ~u : (u | 0x80000000u);
}
DEV_INLINE float funkey(unsigned k) {
  return __uint_as_float((k & 0x80000000u) ? (k & 0x7fffffffu) : ~k);
}

// ---------------------------------------------------------------------------
// Pack [N,3] clouds into float4 for single-load access in ball query.
// ---------------------------------------------------------------------------
__global__ __launch_bounds__(256) void k_pack(PackAll pk, float4* __restrict__ pts4) {
  const PackCfg c = pk.c[blockIdx.y];
  const int j = blockIdx.x * 256 + threadIdx.x;
  if (j >= c.N) return;
  pts4[c.off + j] = make_float4(c.src[3 * j], c.src[3 * j + 1], c.src[3 * j + 2], 0.f);
}

// ---------------------------------------------------------------------------
// Split-scan fused ball query: 8 keypoints/wave, both radii, half-range scan,
// 2-deep register prefetch. Results merged by k_merge.
// ---------------------------------------------------------------------------
__global__ __launch_bounds__(256) void k_ballq3(PairAll pairs, const float* __restrict__ kp,
                                                const float4* __restrict__ pts4,
                                                unsigned short* __restrict__ hidx,
                                                int* __restrict__ hcnt) {
  const PairCfg pc = pairs.p[blockIdx.y];
  const int lane = threadIdx.x & 63;
  const int wave = threadIdx.x >> 6;
  const int w = blockIdx.x * 4 + wave;          // 0..511
  const int half = w >> 8;                      // 0..1
  const int kbase = (w & 255) * 8;
  const int N = pc.N;
  const int Nh = ((N / 2 + 63) / 64) * 64;
  const int start = half ? Nh : 0;
  const int end = half ? N : Nh;
  const float4* __restrict__ pts = pts4 + pc.ptsOff;
  const float r2s = pc.r2s, r2b = pc.r2b;
  const int S0 = pc.S0, S1 = pc.S1;
  const unsigned long long lt = (1ull << lane) - 1ull;

  float qx[8], qy[8], qz[8];
  int cnt0[8], cnt1[8];
  #pragma unroll
  for (int k = 0; k < 8; ++k) {
    qx[k] = kp[(kbase + k) * 3 + 0];
    qy[k] = kp[(kbase + k) * 3 + 1];
    qz[k] = kp[(kbase + k) * 3 + 2];
    cnt0[k] = 0; cnt1[k] = 0;
  }

  unsigned short* outA = hidx + pc.hIdxOff0 + (half * 2048 + kbase) * S0;
  unsigned short* outB = hidx + pc.hIdxOff1 + (half * 2048 + kbase) * S1;

  float4 p0, p1;
  {
    int j0 = start + lane;           p0 = pts[j0 < end ? j0 : end - 1];
    int j1 = start + 64 + lane;      p1 = pts[j1 < end ? j1 : end - 1];
  }
  for (int base = start; base < end; base += 64) {
    const float4 cur = p0;
    p0 = p1;
    {
      int jn = base + 128 + lane;
      p1 = pts[jn < end ? jn : end - 1];
    }
    const int j = base + lane;
    float px = cur.x;
    if (j >= end) px = 3.0e38f;  // mask tail lanes out-of-radius
    const float py = cur.y, pz = cur.z;
    #pragma unroll
    for (int k = 0; k < 8; ++k) {
      float d2;
      {
        #pragma clang fp contract(off)
        const float dx = qx[k] - px;
        const float dy = qy[k] - py;
        const float dz = qz[k] - pz;
        d2 = (dx * dx + dy * dy) + dz * dz;
      }
      const bool in1 = d2 < r2b;
      const unsigned long long m1 = __ballot(in1);
      if (m1) {
        const bool in0 = d2 < r2s;
        const unsigned long long m0 = __ballot(in0);
        if (m0) {
          if (in0) {
            const int pos = cnt0[k] + __popcll(m0 & lt);
            if (pos < S0) outA[k * S0 + pos] = (unsigned short)j;
          }
          cnt0[k] += __popcll(m0);
        }
        if (in1) {
          const int pos = cnt1[k] + __popcll(m1 & lt);
          if (pos < S1) outB[k * S1 + pos] = (unsigned short)j;
        }
        cnt1[k] += __popcll(m1);
      }
    }
    if (((base >> 6) & 3) == 3) {
      bool done = true;
      #pragma unroll
      for (int k = 0; k < 8; ++k) done = done && (cnt0[k] >= S0) && (cnt1[k] >= S1);
      if (done) break;
    }
  }

  if (lane < 8) {
    hcnt[(pc.ci0 * 2 + half) * 2048 + kbase + lane] = cnt0[0];  // placeholder, fixed below
  }
  // write counts (one lane per k to avoid cross-lane gather of per-k regs)
  #pragma unroll
  for (int k = 0; k < 8; ++k) {
    if (lane == 0) {
      hcnt[(pc.ci0 * 2 + half) * 2048 + kbase + k] = cnt0[k];
      hcnt[(pc.ci1 * 2 + half) * 2048 + kbase + k] = cnt1[k];
    }
  }
}

// ---------------------------------------------------------------------------
// Merge half-scans: final ascending idx list + fill + empty mask.
// ---------------------------------------------------------------------------
__global__ __launch_bounds__(256) void k_merge(AllCfg cfgs,
                                               const unsigned short* __restrict__ hidx,
                                               const int* __restrict__ hcnt,
                                               unsigned short* __restrict__ idxbuf,
                                               int* __restrict__ emptybuf) {
  const Cfg cfg = cfgs.c[blockIdx.y];
  const int S = cfg.S;
  const int ci = (int)blockIdx.y;
  const int e = blockIdx.x * 256 + threadIdx.x;
  if (e >= 2048 * S) return;
  const int p = e & (S - 1);
  const int m = e >> cfg.logS;
  const int cA = min(hcnt[(ci * 2 + 0) * 2048 + m], S);
  const int cB = min(hcnt[(ci * 2 + 1) * 2048 + m], S);
  const unsigned short* A = hidx + cfg.hIdxOff + (0 * 2048 + m) * S;
  const unsigned short* B = hidx + cfg.hIdxOff + (1 * 2048 + m) * S;
  const unsigned short first = cA ? A[0] : (cB ? B[0] : (unsigned short)0);
  unsigned short v;
  if (p < cA) v = A[p];
  else if (p - cA < cB) v = B[p - cA];
  else v = first;
  idxbuf[cfg.idxOff + m * S + p] = v;
  if (p == 0) emptybuf[cfg.emptyOff + m] = (cA + cB == 0) ? 1 : 0;
}

// ---------------------------------------------------------------------------
// Old ball query (fallback): one wave per keypoint.
// ---------------------------------------------------------------------------
__global__ __launch_bounds__(256) void k_ballq(AllCfg cfgs, const float* __restrict__ kp,
                                               unsigned short* __restrict__ idxbuf,
                                               int* __restrict__ emptybuf) {
  const Cfg cfg = cfgs.c[blockIdx.y];
  const int lane = threadIdx.x & 63;
  const int wid = (blockIdx.x * blockDim.x + threadIdx.x) >> 6;
  if (wid >= M) return;
  const float qx = kp[wid * 3 + 0], qy = kp[wid * 3 + 1], qz = kp[wid * 3 + 2];
  const int N = cfg.N, S = cfg.S;
  const float r2 = cfg.r2;
  const float* __restrict__ xyz = cfg.xyz;
  unsigned short* out = idxbuf + cfg.idxOff + wid * S;
  int cnt = 0, first = -1;
  for (int base = 0; base < N; base += 64) {
    const int j = base + lane;
    bool inb = false;
    if (j < N) {
      #pragma clang fp contract(off)
      const float dx = qx - xyz[j * 3 + 0];
      const float dy = qy - xyz[j * 3 + 1];
      const float dz = qz - xyz[j * 3 + 2];
      const float d2 = (dx * dx + dy * dy) + dz * dz;
      inb = d2 < r2;
    }
    const unsigned long long msk = __ballot(inb);
    if (msk) {
      if (inb) {
        const int pos = cnt + __popcll(msk & ((1ull << lane) - 1ull));
        if (pos < S) out[pos] = (unsigned short)j;
      }
      if (first < 0) first = base + __builtin_ctzll(msk);
      cnt += __popcll(msk);
      if (cnt >= S) break;
    }
  }
  const unsigned short fillv = (unsigned short)(first < 0 ? 0 : first);
  for (int p = cnt + lane; p < S; p += 64) out[p] = fillv;
  if (lane == 0) emptybuf[cfg.emptyOff + wid] = (first < 0) ? 1 : 0;
}

// ---------------------------------------------------------------------------
// Shared helpers for templated tile kernels
// ---------------------------------------------------------------------------
template<int CIN, int S>
DEV_INLINE void stage_rows(const Cfg& cfg, const float* __restrict__ kp,
                           const unsigned short* __restrict__ idxbuf,
                           const int* __restrict__ emptybuf,
                           int base, float (*in_lds)[(CIN + 3) & ~3]) {
  const int tid = threadIdx.x;
  const int r = tid >> 2, j = tid & 3;
  const int grow = base + r;
  const int m = grow >> ((S == 16) ? 4 : 5);
  const bool emp = emptybuf[cfg.emptyOff + m] != 0;
  const int idx = (int)idxbuf[cfg.idxOff + grow];
  float* dst = in_lds[r];
  if (j == 0) {
    if (emp) { dst[0] = 0.f; dst[1] = 0.f; dst[2] = 0.f; }
    else {
      const float* p = cfg.xyz + 3 * idx;
      dst[0] = p[0] - kp[m * 3 + 0];
      dst[1] = p[1] - kp[m * 3 + 1];
      dst[2] = p[2] - kp[m * 3 + 2];
    }
  }
  if constexpr (CIN > 3) {
    constexpr int CF4 = (CIN - 3) / 4;
    const float4* f4 = (const float4*)cfg.feat + (size_t)idx * CF4;
    for (int c = j; c < CF4; c += 4) {
      float4 v;
      if (emp) v = make_float4(0.f, 0.f, 0.f, 0.f); else v = f4[c];
      dst[3 + 4 * c] = v.x; dst[4 + 4 * c] = v.y;
      dst[5 + 4 * c] = v.z; dst[6 + 4 * c] = v.w;
    }
  }
}

template<int CIN>
DEV_INLINE float dotw(const float* __restrict__ in, const float* __restrict__ w) {
  float h = 0.f;
  #pragma unroll
  for (int ci = 0; ci < CIN; ++ci) h += in[ci] * w[ci];
  return h;
}

DEV_INLINE void stat_reduce_s(float lsum, float lsq, int C0, int cc,
                              float* sA, float* sB, double* gsum, double* gsq) {
  __syncthreads();
  for (int off = 32; off >= C0; off >>= 1) {
    lsum += __shfl_xor(lsum, off);
    lsq  += __shfl_xor(lsq, off);
  }
  if (threadIdx.x < 64) { sA[threadIdx.x] = 0.f; sB[threadIdx.x] = 0.f; }
  __syncthreads();
  if ((int)(threadIdx.x & 63) < C0) { atomicAdd(&sA[cc], lsum); atomicAdd(&sB[cc], lsq); }
  __syncthreads();
  if ((int)threadIdx.x < C0) {
    atomicAdd(&gsum[threadIdx.x], (double)sA[threadIdx.x]);
    atomicAdd(&gsq[threadIdx.x],  (double)sB[threadIdx.x]);
  }
}

// ---------------------------------------------------------------------------
// P1: h0 stats. One 64-row tile per block.
// ---------------------------------------------------------------------------
template<int C0, int CIN, int S>
__device__ __forceinline__ void p1_impl(const Cfg& cfg, const float* __restrict__ kp,
                                        const unsigned short* __restrict__ idxbuf,
                                        const int* __restrict__ emptybuf,
                                        double* __restrict__ stats, char* smem) {
  if ((int)blockIdx.x >= 32 * S) return;
  constexpr int CP = (CIN + 3) & ~3;
  constexpr int STEP = 256 / C0;
  constexpr int RPT = 64 / STEP;
  constexpr int LOGC0 = (C0 == 16) ? 4 : ((C0 == 32) ? 5 : 6);
  float (*in_lds)[CP] = (float(*)[CP])smem;
  const int tid = threadIdx.x;
  const int base = blockIdx.x * 64;
  stage_rows<CIN, S>(cfg, kp, idxbuf, emptybuf, base, in_lds);
  const int cc = tid & (C0 - 1);
  const int rg = tid >> LOGC0;
  float w0[CIN];
  #pragma unroll
  for (int ci = 0; ci < CIN; ++ci) w0[ci] = cfg.W0[ci * C0 + cc];
  __syncthreads();
  float lsum = 0.f, lsq = 0.f;
  for (int rr = 0; rr < RPT; ++rr) {
    const float h = dotw<CIN>(in_lds[rg + rr * STEP], w0);
    lsum += h; lsq += h * h;
  }
  stat_reduce_s(lsum, lsq, C0, cc, (float*)smem, (float*)smem + 64,
                stats + cfg.statOff, stats + cfg.statOff + 64);
}

__global__ __launch_bounds__(256) void k_p1_all(AllCfg cfgs, const float* __restrict__ kp,
                                                const unsigned short* __restrict__ idxbuf,
                                                const int* __restrict__ emptybuf,
                                                double* __restrict__ stats) {
  __shared__ char smem[18432];
  switch (blockIdx.y) {
    case 0: p1_impl<16, 3, 16>(cfgs.c[0], kp, idxbuf, emptybuf, stats, smem); break;
    case 1: p1_impl<16, 3, 16>(cfgs.c[1], kp, idxbuf, emptybuf, stats, smem); break;
    case 2: p1_impl<16, 19, 16>(cfgs.c[2], kp, idxbuf, emptybuf, stats, smem); break;
    case 3: p1_impl<16, 19, 16>(cfgs.c[3], kp, idxbuf, emptybuf, stats, smem); break;
    case 4: p1_impl<32, 35, 16>(cfgs.c[4], kp, idxbuf, emptybuf, stats, smem); break;
    case 5: p1_impl<32, 35, 32>(cfgs.c[5], kp, idxbuf, emptybuf, stats, smem); break;
    case 6: p1_impl<64, 67, 16>(cfgs.c[6], kp, idxbuf, emptybuf, stats, smem); break;
    case 7: p1_impl<64, 67, 32>(cfgs.c[7], kp, idxbuf, emptybuf, stats, smem); break;
    case 8: p1_impl<64, 67, 16>(cfgs.c[8], kp, idxbuf, emptybuf, stats, smem); break;
    case 9: p1_impl<64, 67, 32>(cfgs.c[9], kp, idxbuf, emptybuf, stats, smem); break;
  }
}

// ---------------------------------------------------------------------------
// P2: recompute h0 -> BN0+ReLU -> a0 (LDS) -> h1, h1 stats + per-(m,cc) max/min.
// ---------------------------------------------------------------------------
template<int C0, int CIN, int S>
__device__ __forceinline__ void p2_impl(const Cfg& cfg, const float* __restrict__ kp,
                                        const unsigned short* __restrict__ idxbuf,
                                        const int* __restrict__ emptybuf,
                                        double* __restrict__ stats,
                                        float* __restrict__ maxbuf,
                                        float* __restrict__ minbuf, char* smem) {
  if ((int)blockIdx.x >= 32 * S) return;
  constexpr int CP = (CIN + 3) & ~3;
  constexpr int STEP = 256 / C0;
  constexpr int RPT = 64 / STEP;
  constexpr int LOGC0 = (C0 == 16) ? 4 : ((C0 == 32) ? 5 : 6);
  constexpr int LOGS = (S == 16) ? 4 : 5;
  constexpr int NM = 64 / S;
  float (*in_lds)[CP] = (float(*)[CP])smem;
  float (*a0_lds)[C0] = (float(*)[C0])(smem + 64 * CP * 4);
  unsigned* mxl = (unsigned*)(smem + 64 * CP * 4 + 64 * C0 * 4);
  unsigned* mnl = mxl + NM * C0;
  const int tid = threadIdx.x;
  const int base = blockIdx.x * 64;
  stage_rows<CIN, S>(cfg, kp, idxbuf, emptybuf, base, in_lds);
  if (tid < NM * C0) { mxl[tid] = 0u; mnl[tid] = 0xFFFFFFFFu; }
  const int cc = tid & (C0 - 1);
  const int rg = tid >> LOGC0;
  float w0[CIN], w1[C0];
  #pragma unroll
  for (int ci = 0; ci < CIN; ++ci) w0[ci] = cfg.W0[ci * C0 + cc];
  #pragma unroll
  for (int ci = 0; ci < C0; ++ci) w1[ci] = cfg.W1[ci * C0 + cc];
  const double n = (double)(2048 * S);
  const double* st = stats + cfg.statOff;
  const double mu = st[cc] / n;
  const double var = st[64 + cc] / n - mu * mu;
  const double inv = 1.0 / sqrt(var + 1e-5);
  const double g0 = (double)cfg.gb0[cc], b0 = (double)cfg.gb0[C0 + cc];
  const float sc0 = (float)(inv * g0), sh0 = (float)(b0 - mu * inv * g0);
  __syncthreads();
  for (int rr = 0; rr < RPT; ++rr) {
    const int r = rg + rr * STEP;
    const float h = dotw<CIN>(in_lds[r], w0);
    a0_lds[r][cc] = fmaxf(h * sc0 + sh0, 0.f);
  }
  __syncthreads();
  float lsum = 0.f, lsq = 0.f;
  for (int rr = 0; rr < RPT; ++rr) {
    const int r = rg + rr * STEP;
    float h1 = 0.f;
    #pragma unroll
    for (int ci = 0; ci < C0; ++ci) h1 += a0_lds[r][ci] * w1[ci];
    lsum += h1; lsq += h1 * h1;
    const unsigned k = fkey(h1);
    atomicMax(&mxl[(r >> LOGS) * C0 + cc], k);
    atomicMin(&mnl[(r >> LOGS) * C0 + cc], k);
  }
  stat_reduce_s(lsum, lsq, C0, cc, (float*)in_lds, (float*)in_lds + 64,
                stats + cfg.statOff + 128, stats + cfg.statOff + 192);
  __syncthreads();
  if (tid < NM * C0) {
    const int gcell = (base >> LOGS) * C0 + tid;
    maxbuf[cfg.mmOff + gcell] = funkey(mxl[tid]);
    minbuf[cfg.mmOff + gcell] = funkey(mnl[tid]);
  }
}

__global__ __launch_bounds__(256) void k_p2_all(AllCfg cfgs, const float* __restrict__ kp,
                                                const unsigned short* __restrict__ idxbuf,
                                                const int* __restrict__ emptybuf,
                                                double* __restrict__ stats,
                                                float* __restrict__ maxbuf,
                                                float* __restrict__ minbuf) {
  __shared__ char smem[36864];
  switch (blockIdx.y) {
    case 0: p2_impl<16, 3, 16>(cfgs.c[0], kp, idxbuf, emptybuf, stats, maxbuf, minbuf, smem); break;
    case 1: p2_impl<16, 3, 16>(cfgs.c[1], kp, idxbuf, emptybuf, stats, maxbuf, minbuf, smem); break;
    case 2: p2_impl<16, 19, 16>(cfgs.c[2], kp, idxbuf, emptybuf, stats, maxbuf, minbuf, smem); break;
    case 3: p2_impl<16, 19, 16>(cfgs.c[3], kp, idxbuf, emptybuf, stats, maxbuf, minbuf, smem); break;
    case 4: p2_impl<32, 35, 16>(cfgs.c[4], kp, idxbuf, emptybuf, stats, maxbuf, minbuf, smem); break;
    case 5: p2_impl<32, 35, 32>(cfgs.c[5], kp, idxbuf, emptybuf, stats, maxbuf, minbuf, smem); break;
    case 6: p2_impl<64, 67, 16>(cfgs.c[6], kp, idxbuf, emptybuf, stats, maxbuf, minbuf, smem); break;
    case 7: p2_impl<64, 67, 32>(cfgs.c[7], kp, idxbuf, emptybuf, stats, maxbuf, minbuf, smem); break;
    case 8: p2_impl<64, 67, 16>(cfgs.c[8], kp, idxbuf, emptybuf, stats, maxbuf, minbuf, smem); break;
    case 9: p2_impl<64, 67, 32>(cfgs.c[9], kp, idxbuf, emptybuf, stats, maxbuf, minbuf, smem); break;
  }
}

// ---------------------------------------------------------------------------
// Finalize: apply folded BN1 + ReLU at the h1 extremum (monotone => exact max).
// ---------------------------------------------------------------------------
__global__ __launch_bounds__(256) void k_fin(AllCfg cfgs, const double* __restrict__ stats,
                                             const float* __restrict__ maxbuf,
                                             const float* __restrict__ minbuf,
                                             float* __restrict__ fused) {
  const Cfg cfg = cfgs.c[blockIdx.y];
  const int C0 = cfg.C0;
  const int e = blockIdx.x * 256 + threadIdx.x;
  if (e >= 2048 * C0) return;
  const int cc = e & (C0 - 1);
  const int m = e >> cfg.logC0;
  const double n = (double)(2048 * cfg.S);
  const double* st = stats + cfg.statOff;
  const double mu = st[128 + cc] / n;
  const double v = st[192 + cc] / n - mu * mu;
  const double inv = 1.0 / sqrt(v + 1e-5);
  const double g = (double)cfg.gb1[cc], b = (double)cfg.gb1[C0 + cc];
  const float sc = (float)(inv * g), sh = (float)(b - mu * inv * g);
  const float x = (sc >= 0.f) ? maxbuf[cfg.mmOff + e] : minbuf[cfg.mmOff + e];
  fused[(size_t)m * 512 + cfg.colOff + cc] = fmaxf(sc * x + sh, 0.f);
}

// ---------------------------------------------------------------------------
// Old path (fallback when ws too small): stats0/stats1/final recompute chain.
// ---------------------------------------------------------------------------
DEV_INLINE float h0_elem(const Cfg& cfg, const float* __restrict__ kp,
                         const unsigned short* __restrict__ idxbuf,
                         int row, int co, bool emp) {
  if (emp) return 0.f;
  const int m = row >> cfg.logS;
  const int idx = (int)idxbuf[cfg.idxOff + row];
  const float* p = cfg.xyz + 3 * idx;
  const float gx = p[0] - kp[m * 3 + 0];
  const float gy = p[1] - kp[m * 3 + 1];
  const float gz = p[2] - kp[m * 3 + 2];
  const int C0 = cfg.C0;
  const float* w = cfg.W0 + co;
  float h = gx * w[0] + gy * w[C0] + gz * w[2 * C0];
  const float* f = cfg.feat + (size_t)idx * cfg.Cfeat;
  for (int ci = 0; ci < cfg.Cfeat; ++ci) h += f[ci] * w[(size_t)(3 + ci) * C0];
  return h;
}

DEV_INLINE void stat_reduce(float lsum, float lsq, int C0, int cc,
                            double* gsum, double* gsq) {
  for (int off = 32; off >= C0; off >>= 1) {
    lsum += __shfl_xor(lsum, off);
    lsq  += __shfl_xor(lsq, off);
  }
  __shared__ float sA[64], sB[64];
  if (threadIdx.x < 64) { sA[threadIdx.x] = 0.f; sB[threadIdx.x] = 0.f; }
  __syncthreads();
  if ((int)(threadIdx.x & 63) < C0) { atomicAdd(&sA[cc], lsum); atomicAdd(&sB[cc], lsq); }
  __syncthreads();
  if ((int)threadIdx.x < C0) {
    atomicAdd(&gsum[threadIdx.x], (double)sA[threadIdx.x]);
    atomicAdd(&gsq[threadIdx.x],  (double)sB[threadIdx.x]);
  }
}

__global__ __launch_bounds__(256) void k_stats0(AllCfg cfgs, const float* __restrict__ kp,
                                                const unsigned short* __restrict__ idxbuf,
                                                const int* __restrict__ emptybuf,
                                                double* __restrict__ stats) {
  const Cfg cfg = cfgs.c[blockIdx.y];
  const int C0 = cfg.C0;
  const int total = (M << cfg.logS) << cfg.logC0;
  const int stride = gridDim.x * 256;
  const int t0 = blockIdx.x * 256 + threadIdx.x;
  const int cc = t0 & (C0 - 1);
  float lsum = 0.f, lsq = 0.f;
  for (int e = t0; e < total; e += stride) {
    const int row = e >> cfg.logC0;
    const int m = row >> cfg.logS;
    const bool emp = emptybuf[cfg.emptyOff + m] != 0;
    const float h = h0_elem(cfg, kp, idxbuf, row, cc, emp);
    lsum += h; lsq += h * h;
  }
  stat_reduce(lsum, lsq, C0, cc, stats + cfg.statOff, stats + cfg.statOff + 64);
}

__global__ __launch_bounds__(256) void k_stats1(AllCfg cfgs, const float* __restrict__ kp,
                                                const unsigned short* __restrict__ idxbuf,
                                                const int* __restrict__ emptybuf,
                                                double* __restrict__ stats) {
  const Cfg cfg = cfgs.c[blockIdx.y];
  const int C0 = cfg.C0;
  const int tid = threadIdx.x;
  const int rl = tid >> cfg.logC0;
  const int cc = tid & (C0 - 1);
  const int rpp = 256 >> cfg.logC0;
  const int nrows = M << cfg.logS;
  const double n = (double)nrows;
  const double* st = stats + cfg.statOff;
  const double mu = st[cc] / n;
  const double var = st[64 + cc] / n - mu * mu;
  const double inv = 1.0 / sqrt(var + 1e-5);
  const double g0 = (double)cfg.gb0[cc], b0 = (double)cfg.gb0[C0 + cc];
  const float sc = (float)(inv * g0);
  const float sh = (float)(b0 - mu * inv * g0);
  __shared__ float a0[256];
  float lsum = 0.f, lsq = 0.f;
  const int chunks = nrows >> (8 - cfg.logC0);
  const float* w1 = cfg.W1 + cc;
  for (int ch = blockIdx.x; ch < chunks; ch += gridDim.x) {
    const int row = ch * rpp + rl;
    const int m = row >> cfg.logS;
    const bool emp = emptybuf[cfg.emptyOff + m] != 0;
    const float h = h0_elem(cfg, kp, idxbuf, row, cc, emp);
    a0[tid] = fmaxf(h * sc + sh, 0.f);
    __syncthreads();
    float h1 = 0.f;
    const float* ar = a0 + (tid - cc);
    for (int ci = 0; ci < C0; ++ci) h1 += ar[ci] * w1[(size_t)ci * C0];
    lsum += h1; lsq += h1 * h1;
    __syncthreads();
  }
  stat_reduce(lsum, lsq, C0, cc, stats + cfg.statOff + 128, stats + cfg.statOff + 192);
}

__global__ __launch_bounds__(256) void k_final(AllCfg cfgs, const float* __restrict__ kp,
                                               const unsigned short* __restrict__ idxbuf,
                                               const int* __restrict__ emptybuf,
                                               const double* __restrict__ stats,
                                               float* __restrict__ fused) {
  const Cfg cfg = cfgs.c[blockIdx.y];
  const int C0 = cfg.C0, S = cfg.S;
  const int m = blockIdx.x;
  const int tid = threadIdx.x;
  const int cc = tid & (C0 - 1);
  const int nrows = M << cfg.logS;
  const double n = (double)nrows;
  const double* st = stats + cfg.statOff;
  const double mu0 = st[cc] / n;
  const double v0 = st[64 + cc] / n - mu0 * mu0;
  const double i0 = 1.0 / sqrt(v0 + 1e-5);
  const double g0 = (double)cfg.gb0[cc], b0 = (double)cfg.gb0[C0 + cc];
  const float sc0 = (float)(i0 * g0), sh0 = (float)(b0 - mu0 * i0 * g0);
  const double mu1 = st[128 + cc] / n;
  const double v1 = st[192 + cc] / n - mu1 * mu1;
  const double i1 = 1.0 / sqrt(v1 + 1e-5);
  const double g1 = (double)cfg.gb1[cc], b1 = (double)cfg.gb1[C0 + cc];
  const float sc1 = (float)(i1 * g1), sh1 = (float)(b1 - mu1 * i1 * g1);

  __shared__ float a0[2048];
  __shared__ float mx[64];
  if (tid < 64) mx[tid] = 0.f;
  const bool emp = emptybuf[cfg.emptyOff + m] != 0;
  const int elems = S << cfg.logC0;
  for (int e = tid; e < elems; e += 256) {
    const int s = e >> cfg.logC0;
    const int row = (m << cfg.logS) + s;
    const float h = h0_elem(cfg, kp, idxbuf, row, cc, emp);
    a0[e] = fmaxf(h * sc0 + sh0, 0.f);
  }
  __syncthreads();
  const float* w1 = cfg.W1 + cc;
  for (int e = tid; e < elems; e += 256) {
    const float* ar = a0 + (e - cc);
    float h1 = 0.f;
    for (int ci = 0; ci < C0; ++ci) h1 += ar[ci] * w1[(size_t)ci * C0];
    const float a1v = fmaxf(h1 * sc1 + sh1, 0.f);
    atomicMax((int*)&mx[cc], __float_as_int(a1v));
  }
  __syncthreads();
  if (tid < C0) fused[(size_t)m * 512 + cfg.colOff + tid] = mx[tid];
}

// ---------------------------------------------------------------------------
// BEV bilinear interpolation -> fused cols [0,128)
// ---------------------------------------------------------------------------
__global__ __launch_bounds__(256) void k_bev(const float* __restrict__ kp,
                                             const float* __restrict__ bev,
                                             float* __restrict__ fused) {
  const int e = blockIdx.x * 256 + threadIdx.x;  // 2048*128
  const int c = e & 127, m = e >> 7;
  float x, y;
  {
    #pragma clang fp contract(off)
    x = ((kp[m * 3 + 0] - (-25.6f)) / 0.1f) / 8.0f;
    y = ((kp[m * 3 + 1] - (-25.6f)) / 0.1f) / 8.0f;
  }
  const int x0 = (int)floorf(x), y0 = (int)floorf(y);
  const int x1 = x0 + 1, y1 = y0 + 1;
  const int x0c = min(max(x0, 0), 63), x1c = min(max(x1, 0), 63);
  const int y0c = min(max(y0, 0), 63), y1c = min(max(y1, 0), 63);
  float wa, wb, wc, wd;
  {
    #pragma clang fp contract(off)
    wa = ((float)x1c - x) * ((float)y1c - y);
    wb = ((float)x1c - x) * (y - (float)y0c);
    wc = (x - (float)x0c) * ((float)y1c - y);
    wd = (x - (float)x0c) * (y - (float)y0c);
  }
  const float Ia = bev[((y0c << 6) + x0c) * 128 + c];
  const float Ib = bev[((y1c << 6) + x0c) * 128 + c];
  const float Ic = bev[((y0c << 6) + x1c) * 128 + c];
  const float Id = bev[((y1c << 6) + x1c) * 128 + c];
  {
    #pragma clang fp contract(off)
    fused[(size_t)m * 512 + c] = Ia * wa + Ib * wb + Ic * wc + Id * wd;
  }
}

// ---------------------------------------------------------------------------
// Fusion: h = fused[2048,512] @ fus_W[512,32], stats over M
// ---------------------------------------------------------------------------
__global__ __launch_bounds__(256) void k_fus_mm(const float* __restrict__ fused,
                                               const float* __restrict__ fusW,
                                               float* __restrict__ hbuf,
                                               double* __restrict__ stats) {
  const int e = blockIdx.x * 256 + threadIdx.x;  // 65536
  const int k = e & 31;
  const int m = e >> 5;
  const float* fr = fused + (size_t)m * 512;
  const float* w = fusW + k;
  float h = 0.f;
  for (int c = 0; c < 512; ++c) h += fr[c] * w[(size_t)c * 32];
  hbuf[e] = h;
  stat_reduce(h, h * h, 32, k, stats + 2560, stats + 2560 + 32);
}

__global__ __launch_bounds__(256) void k_fus_out(const float* __restrict__ hbuf,
                                                 const double* __restrict__ stats,
                                                 const float* __restrict__ fgb,
                                                 float* __restrict__ out) {
  const int e = blockIdx.x * 256 + threadIdx.x;
  const int k = e & 31;
  const double n = 2048.0;
  const double* st = stats + 2560;
  const double mu = st[k] / n;
  const double v = st[32 + k] / n - mu * mu;
  const double inv = 1.0 / sqrt(v + 1e-5);
  const double g = (double)fgb[k], b = (double)fgb[32 + k];
  out[e] = fmaxf((float)(inv * g) * hbuf[e] + (float)(b - mu * inv * g), 0.f);
}

// ---------------------------------------------------------------------------
extern "C" void kernel_launch(void* const* d_in, const int* in_sizes, int n_in,
                              void* d_out, int out_size, void* d_ws, size_t ws_size,
                              hipStream_t stream) {
  (void)in_sizes; (void)n_in; (void)out_size;

  const float* kp   = (const float*)d_in[0];
  const float* raw  = (const float*)d_in[1];
  const float* bev  = (const float*)d_in[2];
  const float* c1x  = (const float*)d_in[3];
  const float* c1f  = (const float*)d_in[4];
  const float* c2x  = (const float*)d_in[5];
  const float* c2f  = (const float*)d_in[6];
  const float* c3x  = (const float*)d_in[7];
  const float* c3f  = (const float*)d_in[8];
  const float* c4x  = (const float*)d_in[9];
  const float* c4f  = (const float*)d_in[10];
  const float* fusW = (const float*)d_in[31];
  const float* fgb  = (const float*)d_in[32];

  // ws layout
  char* ws = (char*)d_ws;
  double* stats = (double*)ws;                                  // 2624 doubles
  unsigned short* idxbuf = (unsigned short*)(ws + 32768);       // 10*65536 ushort
  int* emptybuf = (int*)(ws + 32768 + 1310720);                 // 10*2048 int
  float* fused  = (float*)(ws + 1425408);                       // 2048*512 f32
  float* hbuf   = (float*)(ws + 1425408 + 4194304);             // 2048*32 f32
  float* maxbuf = (float*)(ws + 5881856);                       // 786432 f32
  float* minbuf = (float*)(ws + 9027584);                       // 786432 f32
  float4* pts4  = (float4*)(ws + 12173312);                     // 88000 float4
  // half-scan scratch aliases the maxbuf region (dead until k_p2_all)
  int* hcnt = (int*)(ws + 5881856);                             // 10*2*2048 int (163840 B)
  unsigned short* hidx = (unsigned short*)(ws + 5881856 + 163840);  // 2*2048*208 ushort
  const size_t need_old = 5881856;
  const size_t need_new = 12173312;
  const size_t need_bq2 = 12173312 + 1408000;
  if (ws_size < need_old) return;
  const bool fast = (ws_size >= need_new);
  const bool bq3 = (ws_size >= need_bq2) && fast;

  AllCfg cfgs;
  int mmCum = 0, hCum = 0;
  auto setCfg = [&](int i, const float* xyz, const float* feat, int N, int Cf, int C0, int S,
                    double r, const float* W0b, const float* W1b, const float* g0b,
                    const float* g1b, int sIdx, int col) {
    Cfg& c = cfgs.c[i];
    const int Cin = 3 + Cf;
    c.xyz = xyz; c.feat = feat;
    c.W0 = W0b + (size_t)sIdx * Cin * C0;
    c.W1 = W1b + (size_t)sIdx * C0 * C0;
    c.gb0 = g0b + (size_t)sIdx * 2 * C0;
    c.gb1 = g1b + (size_t)sIdx * 2 * C0;
    c.N = N; c.S = S; c.Cfeat = Cf; c.C0 = C0;
    c.logS = (S == 16) ? 4 : 5;
    c.logC0 = (C0 == 16) ? 4 : ((C0 == 32) ? 5 : 6);
    c.colOff = col;
    c.idxOff = i * 65536;
    c.emptyOff = i * 2048;
    c.statOff = i * 256;
    c.mmOff = mmCum;
    mmCum += 2048 * C0;
    c.hIdxOff = hCum;
    hCum += 2 * 2048 * S;
    c.r2 = (float)(r * r);
  };

  const float* rW0 = (const float*)d_in[11]; const float* rW1 = (const float*)d_in[12];
  const float* rg0 = (const float*)d_in[13]; const float* rg1 = (const float*)d_in[14];
  const float* aW0 = (const float*)d_in[15]; const float* aW1 = (const float*)d_in[16];
  const float* ag0 = (const float*)d_in[17]; const float* ag1 = (const float*)d_in[18];
  const float* bW0 = (const float*)d_in[19]; const float* bW1 = (const float*)d_in[20];
  const float* bg0 = (const float*)d_in[21]; const float* bg1 = (const float*)d_in[22];
  const float* cW0 = (const float*)d_in[23]; const float* cW1 = (const float*)d_in[24];
  const float* cg0 = (const float*)d_in[25]; const float* cg1 = (const float*)d_in[26];
  const float* dW0 = (const float*)d_in[27]; const float* dW1 = (const float*)d_in[28];
  const float* dg0 = (const float*)d_in[29]; const float* dg1 = (const float*)d_in[30];

  setCfg(0, raw, nullptr, 30000,  0, 16, 16, 0.4, rW0, rW1, rg0, rg1, 0, 128);
  setCfg(1, raw, nullptr, 30000,  0, 16, 16, 0.8, rW0, rW1, rg0, rg1, 1, 144);
  setCfg(2, c1x, c1f,     30000, 16, 16, 16, 0.4, aW0, aW1, ag0, ag1, 0, 160);
  setCfg(3, c1x, c1f,     30000, 16, 16, 16, 0.8, aW0, aW1, ag0, ag1, 1, 176);
  setCfg(4, c2x, c2f,     16000, 32, 32, 16, 0.8, bW0, bW1, bg0, bg1, 0, 192);
  setCfg(5, c2x, c2f,     16000, 32, 32, 32, 1.2, bW0, bW1, bg0, bg1, 1, 224);
  setCfg(6, c3x, c3f,      8000, 64, 64, 16, 1.2, cW0, cW1, cg0, cg1, 0, 256);
  setCfg(7, c3x, c3f,      8000, 64, 64, 32, 2.4, cW0, cW1, cg0, cg1, 1, 320);
  setCfg(8, c4x, c4f,      4000, 64, 64, 16, 2.4, dW0, dW1, dg0, dg1, 0, 384);
  setCfg(9, c4x, c4f,      4000, 64, 64, 32, 4.8, dW0, dW1, dg0, dg1, 1, 448);

  hipMemsetAsync(stats, 0, 2624 * sizeof(double), stream);

  if (bq3) {
    PackAll pk;
    pk.c[0] = { raw, 30000, 0 };
    pk.c[1] = { c1x, 30000, 30000 };
    pk.c[2] = { c2x, 16000, 60000 };
    pk.c[3] = { c3x,  8000, 76000 };
    pk.c[4] = { c4x,  4000, 84000 };
    PairAll pr;
    auto setPair = [&](int p, int ci0, int ci1, int N, int off) {
      PairCfg& q = pr.p[p];
      q.N = N; q.ptsOff = off;
      q.r2s = cfgs.c[ci0].r2; q.r2b = cfgs.c[ci1].r2;
      q.S0 = cfgs.c[ci0].S;   q.S1 = cfgs.c[ci1].S;
      q.hIdxOff0 = cfgs.c[ci0].hIdxOff; q.hIdxOff1 = cfgs.c[ci1].hIdxOff;
      q.ci0 = ci0; q.ci1 = ci1;
    };
    setPair(0, 0, 1, 30000, 0);
    setPair(1, 2, 3, 30000, 30000);
    setPair(2, 4, 5, 16000, 60000);
    setPair(3, 6, 7,  8000, 76000);
    setPair(4, 8, 9,  4000, 84000);
    k_pack<<<dim3(118, 5), 256, 0, stream>>>(pk, pts4);
    k_ballq3<<<dim3(128, 5), 256, 0, stream>>>(pr, kp, pts4, hidx, hcnt);
    k_merge<<<dim3(256, 10), 256, 0, stream>>>(cfgs, hidx, hcnt, idxbuf, emptybuf);
  } else {
    k_ballq<<<dim3(512, 10), 256, 0, stream>>>(cfgs, kp, idxbuf, emptybuf);
  }

  k_bev<<<dim3(1024), 256, 0, stream>>>(kp, bev, fused);
  if (fast) {
    k_p1_all<<<dim3(1024, 10), 256, 0, stream>>>(cfgs, kp, idxbuf, emptybuf, stats);
    k_p2_all<<<dim3(1024, 10), 256, 0, stream>>>(cfgs, kp, idxbuf, emptybuf, stats, maxbuf, minbuf);
    k_fin<<<dim3(512, 10), 256, 0, stream>>>(cfgs, stats, maxbuf, minbuf, fused);
  } else {
    k_stats0<<<dim3(256, 10), 256, 0, stream>>>(cfgs, kp, idxbuf, emptybuf, stats);
    k_stats1<<<dim3(512, 10), 256, 0, stream>>>(cfgs, kp, idxbuf, emptybuf, stats);
    k_final<<<dim3(2048, 10), 256, 0, stream>>>(cfgs, kp, idxbuf, emptybuf, stats, fused);
  }
  k_fus_mm<<<dim3(256), 256, 0, stream>>>(fused, fusW, hbuf, stats);
  k_fus_out<<<dim3(256), 256, 0, stream>>>(hbuf, stats, fgb, (float*)d_out);
}